// Round 3
// baseline (27546.960 us; speedup 1.0000x reference)
//
#include <hip/hip_runtime.h>
#include <hip/hip_bf16.h>

#define NN 100000   // nodes
#define NE 200000   // bonds
#define NB 600000   // bond neighbours
#define FN 133
#define FB 14
#define FIB 147     // FN+FB
#define DD 256

typedef __hip_bfloat16 bf16;

__device__ __forceinline__ float hswish(float x) {
    float c = fminf(fmaxf(x + 3.f, 0.f), 6.f);
    return x * c * (1.f / 6.f);
}
__device__ __forceinline__ float sigmoidf(float x) {
    return 1.f / (1.f + __expf(-x));
}
__device__ __forceinline__ float bf2f(unsigned short u) {
    union { unsigned int i; float f; } c; c.i = (unsigned int)u << 16; return c.f;
}

// ---------------- fill (zeroing + ws-guard sentinel) --------------------
__global__ __launch_bounds__(256) void fill_kernel(float* __restrict__ p, float v, long n4) {
    long i = (long)blockIdx.x * 256 + threadIdx.x;
    long st = (long)gridDim.x * 256;
    float4 z = {v, v, v, v};
    for (; i < n4; i += st) ((float4*)p)[i] = z;
}

// segment type: 0 = f32 [M,K]; 1 = bf16 [M,K]; 2 = gather node[i_idx[m]] (K=FN); -1 unused
template <int T>
__device__ __forceinline__ float ldseg(const void* p, int K, int m, int k,
                                       const int* lidx, int row0) {
    if constexpr (T == 0) return ((const float*)p)[(size_t)m * K + k];
    else if constexpr (T == 1) return __bfloat162float(((const bf16*)p)[(size_t)m * K + k]);
    else if constexpr (T == 2) return ((const float*)p)[(size_t)lidx[m - row0] * FN + k];
    else return 0.f;
}

// ---------------- generic 3-segment GEMM, 64x64 tile --------------------
// C[M,256] = act( A1@W1 + A2@W2 + A3@W3 + bias )
template <int T1, int T2, int T3, int EP, int OUTBF>   // EP: 0=lin 1=hswish
__global__ __launch_bounds__(256) void gemmX(
    const void* __restrict__ p1, int K1, const float* __restrict__ W1,
    const void* __restrict__ p2, int K2, const float* __restrict__ W2,
    const void* __restrict__ p3, int K3, const float* __restrict__ W3,
    const int* __restrict__ gidx, const float* __restrict__ bias,
    void* __restrict__ Cout, int M)
{
    const int KT = K1 + K2 + K3;
    __shared__ float As[16][68];
    __shared__ float Ws[16][64];
    __shared__ int lidx[64];
    const int tid = threadIdx.x;
    const int row0 = blockIdx.x * 64, col0 = blockIdx.y * 64;
    constexpr bool USEG = (T1 == 2) || (T2 == 2) || (T3 == 2);
    if (USEG) {
        if (tid < 64) { int m = row0 + tid; lidx[tid] = (m < M) ? gidx[m] : 0; }
        __syncthreads();
    }
    const int tx = tid & 15, ty = tid >> 4;
    float acc[4][4] = {};
    const int lm = tid >> 2, lk4 = (tid & 3) * 4;
    const int wk = tid >> 6, wc = tid & 63;

    for (int k0 = 0; k0 < KT; k0 += 16) {
        #pragma unroll
        for (int i = 0; i < 4; i++) {
            int kg = k0 + lk4 + i, m = row0 + lm;
            float v = 0.f;
            if (m < M && kg < KT) {
                if (kg < K1)           v = ldseg<T1>(p1, K1, m, kg, lidx, row0);
                else if (kg < K1 + K2) v = ldseg<T2>(p2, K2, m, kg - K1, lidx, row0);
                else                   v = ldseg<T3>(p3, K3, m, kg - K1 - K2, lidx, row0);
            }
            As[lk4 + i][lm] = v;
        }
        #pragma unroll
        for (int j = 0; j < 4; j++) {
            int kg = k0 + wk + j * 4;
            float v = 0.f;
            if (kg < KT) {
                if (kg < K1)           v = W1[(size_t)kg * DD + col0 + wc];
                else if (kg < K1 + K2) v = W2[(size_t)(kg - K1) * DD + col0 + wc];
                else                   v = W3[(size_t)(kg - K1 - K2) * DD + col0 + wc];
            }
            Ws[wk + j * 4][wc] = v;
        }
        __syncthreads();
        #pragma unroll
        for (int kk = 0; kk < 16; kk++) {
            float4 a4 = *(const float4*)&As[kk][ty * 4];
            float4 b4 = *(const float4*)&Ws[kk][tx * 4];
            float av[4] = {a4.x, a4.y, a4.z, a4.w};
            float bv[4] = {b4.x, b4.y, b4.z, b4.w};
            #pragma unroll
            for (int i = 0; i < 4; i++)
                #pragma unroll
                for (int j = 0; j < 4; j++)
                    acc[i][j] += av[i] * bv[j];
        }
        __syncthreads();
    }

    #pragma unroll
    for (int i = 0; i < 4; i++) {
        int m = row0 + ty * 4 + i;
        if (m >= M) continue;
        #pragma unroll
        for (int j = 0; j < 4; j++) {
            int c = col0 + tx * 4 + j;
            float v = acc[i][j];
            if (bias) v += bias[c];
            if (EP == 1) v = hswish(v);
            size_t idx = (size_t)m * DD + c;
            if (OUTBF) ((bf16*)Cout)[idx] = __float2bfloat16(v);
            else       ((float*)Cout)[idx] = v;
        }
    }
}

// ---------------- fused z+m blend GEMM (dual accumulator) ---------------
// A = [gather-node | bond | S | R] (KT=659)
// z = sigmoid(IB@Wz1 + S@Wz2 + b_z); m = tanh(IB@Wm + R@U + b_m)
// MB(bf16) = (1-z)*S + z*m    (in place: MB never read here)
__global__ __launch_bounds__(256) void blend_kernel(
    const float* __restrict__ node, const float* __restrict__ bondf,
    const int* __restrict__ i_idx,
    const float* __restrict__ S, const float* __restrict__ R,
    const float* __restrict__ w_z, const float* __restrict__ b_z,
    const float* __restrict__ w_m, const float* __restrict__ b_m,
    const float* __restrict__ U,
    bf16* __restrict__ MB)
{
    const int KT = FIB + DD + DD;   // 659
    __shared__ float As[16][68];
    __shared__ float Wz[16][64];
    __shared__ float Wm[16][64];
    __shared__ int lidx[64];
    const int tid = threadIdx.x;
    const int row0 = blockIdx.x * 64, col0 = blockIdx.y * 64;
    if (tid < 64) lidx[tid] = i_idx[row0 + tid];   // NE % 64 == 0
    __syncthreads();
    const int tx = tid & 15, ty = tid >> 4;
    float accz[4][4] = {};
    float accm[4][4] = {};
    const int lm = tid >> 2, lk4 = (tid & 3) * 4;
    const int wk = tid >> 6, wc = tid & 63;

    for (int k0 = 0; k0 < KT; k0 += 16) {
        #pragma unroll
        for (int i = 0; i < 4; i++) {
            int kg = k0 + lk4 + i, m = row0 + lm;
            float v = 0.f;
            if (kg < KT) {
                if (kg < FN)            v = node[(size_t)lidx[lm] * FN + kg];
                else if (kg < FIB)      v = bondf[(size_t)m * FB + (kg - FN)];
                else if (kg < FIB + DD) v = S[(size_t)m * DD + (kg - FIB)];
                else                    v = R[(size_t)m * DD + (kg - FIB - DD)];
            }
            As[lk4 + i][lm] = v;
        }
        #pragma unroll
        for (int j = 0; j < 4; j++) {
            int kg = k0 + wk + j * 4;
            int c = col0 + wc;
            float vz = 0.f, vm = 0.f;
            if (kg < FIB + DD) vz = w_z[(size_t)kg * DD + c];
            if (kg < FIB)      vm = w_m[(size_t)kg * DD + c];
            else if (kg >= FIB + DD && kg < KT)
                               vm = U[(size_t)(kg - FIB - DD) * DD + c];
            Wz[wk + j * 4][wc] = vz;
            Wm[wk + j * 4][wc] = vm;
        }
        __syncthreads();
        #pragma unroll
        for (int kk = 0; kk < 16; kk++) {
            float4 a4 = *(const float4*)&As[kk][ty * 4];
            float4 z4 = *(const float4*)&Wz[kk][tx * 4];
            float4 m4 = *(const float4*)&Wm[kk][tx * 4];
            float av[4] = {a4.x, a4.y, a4.z, a4.w};
            float zv[4] = {z4.x, z4.y, z4.z, z4.w};
            float mv[4] = {m4.x, m4.y, m4.z, m4.w};
            #pragma unroll
            for (int i = 0; i < 4; i++)
                #pragma unroll
                for (int j = 0; j < 4; j++) {
                    accz[i][j] += av[i] * zv[j];
                    accm[i][j] += av[i] * mv[j];
                }
        }
        __syncthreads();
    }

    #pragma unroll
    for (int i = 0; i < 4; i++) {
        int m = row0 + ty * 4 + i;
        #pragma unroll
        for (int j = 0; j < 4; j++) {
            int c = col0 + tx * 4 + j;
            size_t idx = (size_t)m * DD + c;
            float z  = sigmoidf(accz[i][j] + b_z[c]);
            float mm = tanhf(accm[i][j] + b_m[c]);
            MB[idx] = __float2bfloat16((1.f - z) * S[idx] + z * mm);
        }
    }
}

// ------------- fused TR-GEMM + r-scatter (no TR buffer) -----------------
// per neighbour edge e: acc = (MB[ki[e]] @ w_r2)[c];
// r = sigmoid(acc + PR[ij[e]][c]) * MB[ki[e]][c];  R[ij[e]][c] += r
__global__ __launch_bounds__(256) void scat_r_gemm(
    const bf16* __restrict__ MB, const bf16* __restrict__ PR,
    const float* __restrict__ Wr2,
    const int* __restrict__ ij, const int* __restrict__ ki,
    float* __restrict__ R)
{
    __shared__ float As[16][68];
    __shared__ float Ws[16][64];
    __shared__ int lki[64];
    __shared__ int lij[64];
    const int tid = threadIdx.x;
    const int row0 = blockIdx.x * 64, col0 = blockIdx.y * 64;
    if (tid < 64) { lki[tid] = ki[row0 + tid]; lij[tid] = ij[row0 + tid]; }  // NB % 64 == 0
    __syncthreads();
    const int tx = tid & 15, ty = tid >> 4;
    float acc[4][4] = {};
    const int lm = tid >> 2, lk4 = (tid & 3) * 4;
    const int wk = tid >> 6, wc = tid & 63;

    for (int k0 = 0; k0 < DD; k0 += 16) {
        #pragma unroll
        for (int i = 0; i < 4; i++) {
            int kg = k0 + lk4 + i;
            As[lk4 + i][lm] = __bfloat162float(MB[(size_t)lki[lm] * DD + kg]);
        }
        #pragma unroll
        for (int j = 0; j < 4; j++) {
            int kg = k0 + wk + j * 4;
            Ws[wk + j * 4][wc] = Wr2[(size_t)kg * DD + col0 + wc];
        }
        __syncthreads();
        #pragma unroll
        for (int kk = 0; kk < 16; kk++) {
            float4 a4 = *(const float4*)&As[kk][ty * 4];
            float4 b4 = *(const float4*)&Ws[kk][tx * 4];
            float av[4] = {a4.x, a4.y, a4.z, a4.w};
            float bv[4] = {b4.x, b4.y, b4.z, b4.w};
            #pragma unroll
            for (int i = 0; i < 4; i++)
                #pragma unroll
                for (int j = 0; j < 4; j++)
                    acc[i][j] += av[i] * bv[j];
        }
        __syncthreads();
    }

    #pragma unroll
    for (int i = 0; i < 4; i++) {
        int e = ty * 4 + i;
        int src = lki[e], seg = lij[e];
        #pragma unroll
        for (int j = 0; j < 4; j++) {
            int c = col0 + tx * 4 + j;
            float mb = __bfloat162float(MB[(size_t)src * DD + c]);
            float pr = __bfloat162float(PR[(size_t)seg * DD + c]);
            float r = sigmoidf(acc[i][j] + pr) * mb;
            atomicAdd(&R[(size_t)seg * DD + c], r);
        }
    }
}

// ---------------- full-row f32 GEMM (in-place safe) ---------------------
// out[M,256] = hsw(A1@W1 + A2@W2 + A3@W3 + bias); A2/A3 are [M,256] f32.
__global__ __launch_bounds__(256) void noderow_kernel(
    const float* __restrict__ A1, int K1, const float* __restrict__ W1,
    const float* __restrict__ A2, const float* __restrict__ W2,
    const float* __restrict__ A3, const float* __restrict__ W3,
    int K2, int K3,
    const float* __restrict__ bias, float* __restrict__ out, int M)
{
    const int KT = K1 + K2 + K3;
    __shared__ float As[16][68];
    __shared__ float Ws[16][256];
    const int tid = threadIdx.x;
    const int row0 = blockIdx.x * 64;
    const int tx = tid & 15, ty = tid >> 4;
    float acc[4][16] = {};
    const int lm = tid >> 2, lk4 = (tid & 3) * 4;
    const int wr = tid >> 4, wc0 = (tid & 15) * 16;

    for (int k0 = 0; k0 < KT; k0 += 16) {
        #pragma unroll
        for (int i = 0; i < 4; i++) {
            int kg = k0 + lk4 + i, m = row0 + lm;
            float v = 0.f;
            if (m < M && kg < KT) {
                if (kg < K1)           v = A1[(size_t)m * K1 + kg];
                else if (kg < K1 + K2) v = A2[(size_t)m * DD + (kg - K1)];
                else                   v = A3[(size_t)m * DD + (kg - K1 - K2)];
            }
            As[lk4 + i][lm] = v;
        }
        {
            int kg = k0 + wr;
            #pragma unroll
            for (int j = 0; j < 16; j++) {
                int c = wc0 + j;
                float v = 0.f;
                if (kg < KT) {
                    if (kg < K1)           v = W1[(size_t)kg * DD + c];
                    else if (kg < K1 + K2) v = W2[(size_t)(kg - K1) * DD + c];
                    else                   v = W3[(size_t)(kg - K1 - K2) * DD + c];
                }
                Ws[wr][c] = v;
            }
        }
        __syncthreads();
        #pragma unroll
        for (int kk = 0; kk < 16; kk++) {
            float4 a4 = *(const float4*)&As[kk][ty * 4];
            float av[4] = {a4.x, a4.y, a4.z, a4.w};
            float wv[16];
            #pragma unroll
            for (int j4 = 0; j4 < 4; j4++) {
                float4 w4 = *(const float4*)&Ws[kk][tx * 16 + j4 * 4];
                wv[j4 * 4 + 0] = w4.x; wv[j4 * 4 + 1] = w4.y;
                wv[j4 * 4 + 2] = w4.z; wv[j4 * 4 + 3] = w4.w;
            }
            #pragma unroll
            for (int i = 0; i < 4; i++)
                #pragma unroll
                for (int j = 0; j < 16; j++)
                    acc[i][j] += av[i] * wv[j];
        }
        __syncthreads();
    }

    #pragma unroll
    for (int i = 0; i < 4; i++) {
        int m = row0 + ty * 4 + i;
        if (m >= M) continue;
        #pragma unroll
        for (int j = 0; j < 16; j++) {
            int c = tx * 16 + j;
            out[(size_t)m * DD + c] = hswish(acc[i][j] + bias[c]);
        }
    }
}

// ---------------- scatters (bf16 source, f32 atomics) -------------------
__global__ __launch_bounds__(256) void scatter_s_kernel(
    const bf16* __restrict__ MB, const int* __restrict__ ij,
    const int* __restrict__ ki, float* __restrict__ S)
{
    int t = blockIdx.x * 256 + threadIdx.x;
    int e = t >> 6;
    if (e >= NB) return;
    int lane = t & 63;
    int seg = ij[e], src = ki[e];
    const ushort4 u = *(const ushort4*)((const unsigned short*)MB + (size_t)src * DD + lane * 4);
    float* dst = &S[(size_t)seg * DD + lane * 4];
    atomicAdd(dst + 0, bf2f(u.x)); atomicAdd(dst + 1, bf2f(u.y));
    atomicAdd(dst + 2, bf2f(u.z)); atomicAdd(dst + 3, bf2f(u.w));
}

__global__ __launch_bounds__(256) void scatter_agg_kernel(
    const bf16* __restrict__ MB, const int* __restrict__ jidx,
    float* __restrict__ AGG)
{
    int t = blockIdx.x * 256 + threadIdx.x;
    int e = t >> 6;
    if (e >= NE) return;
    int lane = t & 63;
    int seg = jidx[e];
    const ushort4 u = *(const ushort4*)((const unsigned short*)MB + (size_t)e * DD + lane * 4);
    float* dst = &AGG[(size_t)seg * DD + lane * 4];
    atomicAdd(dst + 0, bf2f(u.x)); atomicAdd(dst + 1, bf2f(u.y));
    atomicAdd(dst + 2, bf2f(u.z)); atomicAdd(dst + 3, bf2f(u.w));
}

extern "C" void kernel_launch(void* const* d_in, const int* in_sizes, int n_in,
                              void* d_out, int out_size, void* d_ws, size_t ws_size,
                              hipStream_t stream)
{
    const float* node  = (const float*)d_in[0];
    const float* bond  = (const float*)d_in[1];
    const int* connect = (const int*)d_in[2];
    const int* bnb     = (const int*)d_in[3];
    const float* w_node       = (const float*)d_in[4];
    const float* b_node       = (const float*)d_in[5];
    const float* w_node_final = (const float*)d_in[6];
    const float* b_node_final = (const float*)d_in[7];
    const float* w_bond       = (const float*)d_in[8];
    const float* b_bond       = (const float*)d_in[9];
    const float* w_bond_final = (const float*)d_in[10];
    const float* b_bond_final = (const float*)d_in[11];
    const float* w_z = (const float*)d_in[12];
    const float* b_z = (const float*)d_in[13];
    const float* w_r = (const float*)d_in[14];
    const float* b_r = (const float*)d_in[15];
    const float* u_  = (const float*)d_in[16];
    const float* w_m = (const float*)d_in[17];
    const float* b_m = (const float*)d_in[18];
    const float* w_n = (const float*)d_in[19];
    const float* b_n = (const float*)d_in[20];
    const float* u_n = (const float*)d_in[21];

    const int* i_idx = connect;            // connect[0]
    const int* j_idx = connect + NE;       // connect[1]
    const int* ij    = bnb;                // bond_neighbour[0]
    const int* ki    = bnb + NB;           // bond_neighbour[1]

    // ---- workspace: PR(bf16) | MB(bf16) | S(f32, AGG aliases) = 409.6 MB
    const size_t B_PR = (size_t)NE * DD * 2;   // 102,400,000
    const size_t B_MB = (size_t)NE * DD * 2;   // 102,400,000
    const size_t B_S  = (size_t)NE * DD * 4;   // 204,800,000
    const size_t NEED = B_PR + B_MB + B_S;     // 409,600,000

    float* out_node = (float*)d_out;                       // MN lives here
    float* out_bond = out_node + (size_t)NN * DD;          // R lives here

    if (ws_size < NEED) {   // diagnostic sentinel: absmax ~1e6 => ws too small
        fill_kernel<<<2048, 256, 0, stream>>>((float*)d_out, 1e6f, (long)out_size / 4);
        return;
    }

    char* base = (char*)d_ws;
    bf16* PR = (bf16*)base;
    bf16* MB = (bf16*)(base + B_PR);
    float* S = (float*)(base + B_PR + B_MB);
    float* AGG = S;                 // S dead after blend; AGG fits in its first half
    float* MN = out_node;
    float* R  = out_bond;

    dim3 gB(NE / 64, 4);            // 3125 x 4
    dim3 gN((NN + 63) / 64, 4);     // 1563 x 4
    dim3 gR(NB / 64, 4);            // 9375 x 4
    int gNU = (NN + 63) / 64;
    int blkS   = NB * 64 / 256;     // 150000
    int blkAGG = NE * 64 / 256;     // 50000

    const float* w_r2 = w_r + (size_t)FIB * DD;

    // hoisted, layer-invariant
    gemmX<0, -1, -1, 1, 0><<<gN, 256, 0, stream>>>(
        node, FN, w_node, nullptr, 0, nullptr, nullptr, 0, nullptr,
        nullptr, b_node, MN, NN);
    gemmX<2, 0, -1, 0, 1><<<gB, 256, 0, stream>>>(
        node, FN, w_r, bond, FB, w_r + (size_t)FN * DD, nullptr, 0, nullptr,
        i_idx, b_r, PR, NE);
    gemmX<2, 0, -1, 1, 1><<<gB, 256, 0, stream>>>(
        node, FN, w_bond, bond, FB, w_bond + (size_t)FN * DD, nullptr, 0, nullptr,
        i_idx, b_bond, MB, NE);

    for (int l = 0; l < 3; l++) {
        fill_kernel<<<2048, 256, 0, stream>>>(S, 0.f, (long)NE * DD / 4);
        scatter_s_kernel<<<blkS, 256, 0, stream>>>(MB, ij, ki, S);
        fill_kernel<<<2048, 256, 0, stream>>>(R, 0.f, (long)NE * DD / 4);
        scat_r_gemm<<<gR, 256, 0, stream>>>(MB, PR, w_r2, ij, ki, R);
        blend_kernel<<<gB, 256, 0, stream>>>(node, bond, i_idx, S, R,
                                             w_z, b_z, w_m, b_m, u_, MB);
        fill_kernel<<<2048, 256, 0, stream>>>(AGG, 0.f, (long)NN * DD / 4);
        scatter_agg_kernel<<<blkAGG, 256, 0, stream>>>(MB, j_idx, AGG);
        noderow_kernel<<<gNU, 256, 0, stream>>>(
            node, FN, w_n, MN, u_n, AGG, u_n + (size_t)DD * DD, DD, DD,
            b_n, MN, NN);
    }

    gemmX<2, 0, 1, 1, 0><<<gB, 256, 0, stream>>>(
        node, FN, w_bond_final, bond, FB, w_bond_final + (size_t)FN * DD,
        MB, DD, w_bond_final + (size_t)FIB * DD,
        i_idx, b_bond_final, out_bond, NE);
    noderow_kernel<<<gNU, 256, 0, stream>>>(
        node, FN, w_node_final, MN, w_node_final + (size_t)FN * DD,
        nullptr, nullptr, DD, 0, b_node_final, out_node, NN);
}

// Round 4
// 17153.728 us; speedup vs baseline: 1.6059x; 1.6059x over previous
//
#include <hip/hip_runtime.h>
#include <hip/hip_bf16.h>

#define NN 100000   // nodes
#define NE 200000   // bonds
#define NB 600000   // bond neighbours
#define FN 133
#define FB 14
#define FIB 147     // FN+FB
#define DD 256

typedef __hip_bfloat16 bf16;
typedef __attribute__((ext_vector_type(8))) short short8;   // 8 bf16 = 4 VGPR
typedef __attribute__((ext_vector_type(4))) float f32x4;

__device__ __forceinline__ float hswish(float x) {
    float c = fminf(fmaxf(x + 3.f, 0.f), 6.f);
    return x * c * (1.f / 6.f);
}
__device__ __forceinline__ float sigmoidf(float x) {
    return 1.f / (1.f + __expf(-x));
}
__device__ __forceinline__ float bf2f(unsigned short u) {
    union { unsigned int i; float f; } c; c.i = (unsigned int)u << 16; return c.f;
}
__device__ __forceinline__ unsigned short f2bf(float v) {
    bf16 b = __float2bfloat16(v);
    unsigned short u; __builtin_memcpy(&u, &b, 2); return u;
}

// ---------------- fill (zeroing + ws-guard sentinel) --------------------
__global__ __launch_bounds__(256) void fill_kernel(float* __restrict__ p, float v, long n4) {
    long i = (long)blockIdx.x * 256 + threadIdx.x;
    long st = (long)gridDim.x * 256;
    float4 z = {v, v, v, v};
    for (; i < n4; i += st) ((float4*)p)[i] = z;
}

// ------------- weight pack: dst[n][k] = bf16(seg(k, n)), K-padded -------
__global__ __launch_bounds__(256) void pack_wt(
    const float* W1, int K1, const float* W2, int K2, const float* W3, int K3,
    int KTpad, bf16* dst)
{
    int idx = blockIdx.x * 256 + threadIdx.x;
    if (idx >= 256 * KTpad) return;
    int n = idx / KTpad, k = idx % KTpad;
    float v = 0.f;
    if (k < K1)                { if (W1) v = W1[(size_t)k * DD + n]; }
    else if (k < K1 + K2)      { if (W2) v = W2[(size_t)(k - K1) * DD + n]; }
    else if (k < K1 + K2 + K3) { if (W3) v = W3[(size_t)(k - K1 - K2) * DD + n]; }
    dst[(size_t)n * KTpad + k] = __float2bfloat16(v);
}

// segment element load. T: -1 unused, 0 f32, 1 bf16, 2 f32-gather, 3 bf16-gather
template <int T>
__device__ __forceinline__ float ldA(const void* p, int K, int mg, int mloc,
                                     const int* lidx, int k) {
    if constexpr (T < 0) { return 0.f; }
    else {
        int r = (T >= 2) ? lidx[mloc] : mg;
        if constexpr (T == 0 || T == 2) return ((const float*)p)[(size_t)r * K + k];
        else return __bfloat162float(((const bf16*)p)[(size_t)r * K + k]);
    }
}

// ---------------- MFMA GEMM, BM=128 x BN, K-step 32 ---------------------
// EP: 0 lin->bf16, 1 hsw->bf16, 2 hsw->f32, 3 blend (dual-W) -> bf16,
//     4 scatR: r = sigmoid(acc + PR[ij]) * MB[ki]; atomicAdd R[ij]
template <int BN, int T1, int T2, int T3, int T4, int EP>
__global__ __launch_bounds__(BN == 256 ? 512 : 256) void mgemm(
    const void* __restrict__ p1, int K1, const void* __restrict__ p2, int K2,
    const void* __restrict__ p3, int K3, const void* __restrict__ p4, int K4,
    const int* __restrict__ gidx, const int* __restrict__ ijix,
    const bf16* __restrict__ WT1, const bf16* __restrict__ WT2, int KTpad,
    const float* __restrict__ bias1, const float* __restrict__ bias2,
    const float* __restrict__ Sbuf, const bf16* __restrict__ PRb,
    const bf16* __restrict__ MBb,
    void* __restrict__ outp, float* __restrict__ Rb, int M)
{
    constexpr int BM = 128;
    constexpr int NT = (BN == 256) ? 512 : 256;
    constexpr int nWc = BN / 64;
    const int KT = K1 + K2 + K3 + K4;
    __shared__ __align__(16) unsigned short As[BM * 40];
    __shared__ __align__(16) unsigned short Bs[BN * 40];
    __shared__ __align__(16) unsigned short Bs2[(EP == 3 ? BN : 8) * 40];
    __shared__ int lidx[BM];
    __shared__ int lij[(EP == 4) ? BM : 8];
    const int tid = threadIdx.x;
    const int row0 = blockIdx.x * BM, col0 = blockIdx.y * BN;
    constexpr bool G = (T1 >= 2) || (T2 >= 2) || (T3 >= 2) || (T4 >= 2);
    if (G && tid < BM)       { int m = row0 + tid; lidx[tid] = (m < M) ? gidx[m] : 0; }
    if (EP == 4 && tid < BM) { int m = row0 + tid; lij[tid]  = (m < M) ? ijix[m] : 0; }
    __syncthreads();

    f32x4 acc[4][4] = {};
    f32x4 acc2[4][4] = {};
    const int lane = tid & 63, w = tid >> 6;
    const int wr = w / nWc, wc = w % nWc;
    const int fr = lane & 15, ko = (lane >> 4) * 8;

    for (int k0 = 0; k0 < KTpad; k0 += 32) {
        // ---- A stage: 128x32 bf16, stride-40 padded rows
        #pragma unroll
        for (int it = 0; it < BM / (NT / 4); ++it) {
            int mloc = (tid >> 2) + it * (NT / 4);
            int mg = row0 + mloc;
            int kq = (tid & 3) * 8;
            unsigned short us[8];
            #pragma unroll
            for (int j = 0; j < 8; j++) {
                int kg = k0 + kq + j;
                float v = 0.f;
                if (mg < M && kg < KT) {
                    if (kg < K1)                v = ldA<T1>(p1, K1, mg, mloc, lidx, kg);
                    else if (kg < K1 + K2)      v = ldA<T2>(p2, K2, mg, mloc, lidx, kg - K1);
                    else if (kg < K1 + K2 + K3) v = ldA<T3>(p3, K3, mg, mloc, lidx, kg - K1 - K2);
                    else                        v = ldA<T4>(p4, K4, mg, mloc, lidx, kg - K1 - K2 - K3);
                }
                us[j] = f2bf(v);
            }
            uint4 pk;
            pk.x = us[0] | ((unsigned)us[1] << 16); pk.y = us[2] | ((unsigned)us[3] << 16);
            pk.z = us[4] | ((unsigned)us[5] << 16); pk.w = us[6] | ((unsigned)us[7] << 16);
            *(uint4*)&As[mloc * 40 + kq] = pk;
        }
        // ---- B stage: WT[n][k] bf16 (pre-packed, aligned) -> Bs[n][k]
        #pragma unroll
        for (int it = 0; it < BN / (NT / 4); ++it) {
            int nloc = (tid >> 2) + it * (NT / 4);
            int kq = (tid & 3) * 8;
            *(uint4*)&Bs[nloc * 40 + kq] =
                *(const uint4*)&WT1[(size_t)(col0 + nloc) * KTpad + k0 + kq];
            if (EP == 3)
                *(uint4*)&Bs2[nloc * 40 + kq] =
                    *(const uint4*)&WT2[(size_t)(col0 + nloc) * KTpad + k0 + kq];
        }
        __syncthreads();
        short8 a[4], b[4], b2[4];
        #pragma unroll
        for (int m = 0; m < 4; m++)
            a[m] = *(const short8*)&As[(wr * 64 + m * 16 + fr) * 40 + ko];
        #pragma unroll
        for (int n = 0; n < 4; n++) {
            b[n] = *(const short8*)&Bs[(wc * 64 + n * 16 + fr) * 40 + ko];
            if (EP == 3)
                b2[n] = *(const short8*)&Bs2[(wc * 64 + n * 16 + fr) * 40 + ko];
        }
        #pragma unroll
        for (int m = 0; m < 4; m++)
            #pragma unroll
            for (int n = 0; n < 4; n++) {
                acc[m][n] = __builtin_amdgcn_mfma_f32_16x16x32_bf16(a[m], b[n], acc[m][n], 0, 0, 0);
                if (EP == 3)
                    acc2[m][n] = __builtin_amdgcn_mfma_f32_16x16x32_bf16(a[m], b2[n], acc2[m][n], 0, 0, 0);
            }
        __syncthreads();
    }

    // ---- epilogue. D layout: col = lane&15, row = (lane>>4)*4 + i
    #pragma unroll
    for (int m = 0; m < 4; m++) {
        #pragma unroll
        for (int i = 0; i < 4; i++) {
            int mloc = wr * 64 + m * 16 + (lane >> 4) * 4 + i;
            int gm = row0 + mloc;
            if (gm >= M) continue;
            #pragma unroll
            for (int n = 0; n < 4; n++) {
                int gc = col0 + wc * 64 + n * 16 + (lane & 15);
                float v = acc[m][n][i];
                if (EP == 0 || EP == 1 || EP == 2) {
                    if (bias1) v += bias1[gc];
                    if (EP != 0) v = hswish(v);
                    if (EP == 2) ((float*)outp)[(size_t)gm * DD + gc] = v;
                    else         ((bf16*)outp)[(size_t)gm * DD + gc] = __float2bfloat16(v);
                } else if (EP == 3) {
                    float z  = sigmoidf(v + bias1[gc]);
                    float mm = tanhf(acc2[m][n][i] + bias2[gc]);
                    float s  = Sbuf[(size_t)gm * DD + gc];
                    ((bf16*)outp)[(size_t)gm * DD + gc] =
                        __float2bfloat16((1.f - z) * s + z * mm);
                } else {  // EP == 4
                    int seg = lij[mloc], src = lidx[mloc];
                    float pr = __bfloat162float(PRb[(size_t)seg * DD + gc]);
                    float mb = __bfloat162float(MBb[(size_t)src * DD + gc]);
                    float r = sigmoidf(v + pr) * mb;
                    atomicAdd(&Rb[(size_t)seg * DD + gc], r);
                }
            }
        }
    }
}

// ---------------- scatters (bf16 source, f32 atomics) -------------------
__global__ __launch_bounds__(256) void scatter_s_kernel(
    const bf16* __restrict__ MB, const int* __restrict__ ij,
    const int* __restrict__ ki, float* __restrict__ S)
{
    int t = blockIdx.x * 256 + threadIdx.x;
    int e = t >> 6;
    if (e >= NB) return;
    int lane = t & 63;
    int seg = ij[e], src = ki[e];
    const ushort4 u = *(const ushort4*)((const unsigned short*)MB + (size_t)src * DD + lane * 4);
    float* dst = &S[(size_t)seg * DD + lane * 4];
    atomicAdd(dst + 0, bf2f(u.x)); atomicAdd(dst + 1, bf2f(u.y));
    atomicAdd(dst + 2, bf2f(u.z)); atomicAdd(dst + 3, bf2f(u.w));
}

__global__ __launch_bounds__(256) void scatter_agg_kernel(
    const bf16* __restrict__ MB, const int* __restrict__ jidx,
    float* __restrict__ AGG)
{
    int t = blockIdx.x * 256 + threadIdx.x;
    int e = t >> 6;
    if (e >= NE) return;
    int lane = t & 63;
    int seg = jidx[e];
    const ushort4 u = *(const ushort4*)((const unsigned short*)MB + (size_t)e * DD + lane * 4);
    float* dst = &AGG[(size_t)seg * DD + lane * 4];
    atomicAdd(dst + 0, bf2f(u.x)); atomicAdd(dst + 1, bf2f(u.y));
    atomicAdd(dst + 2, bf2f(u.z)); atomicAdd(dst + 3, bf2f(u.w));
}

extern "C" void kernel_launch(void* const* d_in, const int* in_sizes, int n_in,
                              void* d_out, int out_size, void* d_ws, size_t ws_size,
                              hipStream_t stream)
{
    const float* node  = (const float*)d_in[0];
    const float* bond  = (const float*)d_in[1];
    const int* connect = (const int*)d_in[2];
    const int* bnb     = (const int*)d_in[3];
    const float* w_node       = (const float*)d_in[4];
    const float* b_node       = (const float*)d_in[5];
    const float* w_node_final = (const float*)d_in[6];
    const float* b_node_final = (const float*)d_in[7];
    const float* w_bond       = (const float*)d_in[8];
    const float* b_bond       = (const float*)d_in[9];
    const float* w_bond_final = (const float*)d_in[10];
    const float* b_bond_final = (const float*)d_in[11];
    const float* w_z = (const float*)d_in[12];
    const float* b_z = (const float*)d_in[13];
    const float* w_r = (const float*)d_in[14];
    const float* b_r = (const float*)d_in[15];
    const float* u_  = (const float*)d_in[16];
    const float* w_m = (const float*)d_in[17];
    const float* b_m = (const float*)d_in[18];
    const float* w_n = (const float*)d_in[19];
    const float* b_n = (const float*)d_in[20];
    const float* u_n = (const float*)d_in[21];

    const int* i_idx = connect;            // connect[0]
    const int* j_idx = connect + NE;       // connect[1]
    const int* ij    = bnb;                // bond_neighbour[0]
    const int* ki    = bnb + NB;           // bond_neighbour[1]

    // ---- workspace: PR(bf16) | MB(bf16) | S(f32) | packed bf16 weights
    const size_t B_PR = (size_t)NE * DD * 2;       // 102,400,000
    const size_t B_MB = (size_t)NE * DD * 2;       // 102,400,000
    const size_t B_S  = (size_t)NE * DD * 4;       // 204,800,000
    const size_t B_WT = 1835008;                   // all packed weights
    const size_t NEED = B_PR + B_MB + B_S + B_WT;  // ~411.4 MB

    float* out_node = (float*)d_out;               // MN lives here
    float* out_bond = out_node + (size_t)NN * DD;  // R lives here

    if (ws_size < NEED) {   // diagnostic sentinel
        fill_kernel<<<2048, 256, 0, stream>>>((float*)d_out, 1e6f, (long)out_size / 4);
        return;
    }

    char* base = (char*)d_ws;
    bf16* PR = (bf16*)base;
    bf16* MB = (bf16*)(base + B_PR);
    float* S = (float*)(base + B_PR + B_MB);
    float* AGG = S;                 // S dead after blend; AGG in its first half
    float* MN = out_node;
    float* R  = out_bond;

    char* wt = base + B_PR + B_MB + B_S;
    auto wtAlloc = [&](size_t elems) { bf16* p = (bf16*)wt; wt += elems * 2; return p; };
    bf16* WTz  = wtAlloc(672 * 256);   // w_z rows 0..402 over [node|bond|S], R part 0
    bf16* WTm  = wtAlloc(672 * 256);   // w_m(147) | zeros(256) | u(256)
    bf16* WTnu = wtAlloc(672 * 256);   // w_n(133) | u_n(512)
    bf16* WTr2 = wtAlloc(256 * 256);   // w_r rows 147..402
    bf16* WTr  = wtAlloc(160 * 256);   // w_r rows 0..146
    bf16* WTb  = wtAlloc(160 * 256);   // w_bond(147)
    bf16* WTn0 = wtAlloc(160 * 256);   // w_node(133)
    bf16* WTbf = wtAlloc(416 * 256);   // w_bond_final(403)
    bf16* WTnf = wtAlloc(416 * 256);   // w_node_final(389)

    const float* w_r2 = w_r + (size_t)FIB * DD;

    auto packG = [&](int ktpad) { return (256 * ktpad + 255) / 256; };
    pack_wt<<<packG(672), 256, 0, stream>>>(w_z, 403, nullptr, 0, nullptr, 0, 672, WTz);
    pack_wt<<<packG(672), 256, 0, stream>>>(w_m, FIB, nullptr, DD, u_, DD, 672, WTm);
    pack_wt<<<packG(672), 256, 0, stream>>>(w_n, FN, u_n, 2 * DD, nullptr, 0, 672, WTnu);
    pack_wt<<<packG(256), 256, 0, stream>>>(w_r2, DD, nullptr, 0, nullptr, 0, 256, WTr2);
    pack_wt<<<packG(160), 256, 0, stream>>>(w_r, FIB, nullptr, 0, nullptr, 0, 160, WTr);
    pack_wt<<<packG(160), 256, 0, stream>>>(w_bond, FIB, nullptr, 0, nullptr, 0, 160, WTb);
    pack_wt<<<packG(160), 256, 0, stream>>>(w_node, FN, nullptr, 0, nullptr, 0, 160, WTn0);
    pack_wt<<<packG(416), 256, 0, stream>>>(w_bond_final, 403, nullptr, 0, nullptr, 0, 416, WTbf);
    pack_wt<<<packG(416), 256, 0, stream>>>(w_node_final, 389, nullptr, 0, nullptr, 0, 416, WTnf);

    dim3 gB((NE + 127) / 128, 2);     // 1563 x 2
    dim3 gN((NN + 127) / 128, 2);     // 782 x 2
    dim3 gNB((NB + 127) / 128, 2);    // 4688 x 2
    dim3 gNfull((NN + 127) / 128, 1); // 782, BN=256
    int blkS   = NB * 64 / 256;
    int blkAGG = NE * 64 / 256;

    // hoisted, layer-invariant
    mgemm<128, 0, -1, -1, -1, 2><<<gN, 256, 0, stream>>>(
        node, FN, nullptr, 0, nullptr, 0, nullptr, 0, nullptr, nullptr,
        WTn0, nullptr, 160, b_node, nullptr, nullptr, nullptr, nullptr, MN, nullptr, NN);
    mgemm<128, 2, 0, -1, -1, 0><<<gB, 256, 0, stream>>>(
        node, FN, bond, FB, nullptr, 0, nullptr, 0, i_idx, nullptr,
        WTr, nullptr, 160, b_r, nullptr, nullptr, nullptr, nullptr, PR, nullptr, NE);
    mgemm<128, 2, 0, -1, -1, 1><<<gB, 256, 0, stream>>>(
        node, FN, bond, FB, nullptr, 0, nullptr, 0, i_idx, nullptr,
        WTb, nullptr, 160, b_bond, nullptr, nullptr, nullptr, nullptr, MB, nullptr, NE);

    for (int l = 0; l < 3; l++) {
        fill_kernel<<<2048, 256, 0, stream>>>(S, 0.f, (long)NE * DD / 4);
        scatter_s_kernel<<<blkS, 256, 0, stream>>>(MB, ij, ki, S);
        fill_kernel<<<2048, 256, 0, stream>>>(R, 0.f, (long)NE * DD / 4);
        mgemm<128, 3, -1, -1, -1, 4><<<gNB, 256, 0, stream>>>(
            MB, DD, nullptr, 0, nullptr, 0, nullptr, 0, ki, ij,
            WTr2, nullptr, 256, nullptr, nullptr, nullptr, PR, MB, nullptr, R, NB);
        mgemm<128, 2, 0, 0, 0, 3><<<gB, 256, 0, stream>>>(
            node, FN, bond, FB, S, DD, R, DD, i_idx, nullptr,
            WTz, WTm, 672, b_z, b_m, S, nullptr, nullptr, MB, nullptr, NE);
        fill_kernel<<<2048, 256, 0, stream>>>(AGG, 0.f, (long)NN * DD / 4);
        scatter_agg_kernel<<<blkAGG, 256, 0, stream>>>(MB, j_idx, AGG);
        mgemm<256, 0, 0, 0, -1, 2><<<gNfull, 512, 0, stream>>>(
            node, FN, MN, DD, AGG, DD, nullptr, 0, nullptr, nullptr,
            WTnu, nullptr, 672, b_n, nullptr, nullptr, nullptr, nullptr, MN, nullptr, NN);
    }

    mgemm<128, 2, 0, 1, -1, 2><<<gB, 256, 0, stream>>>(
        node, FN, bond, FB, MB, DD, nullptr, 0, i_idx, nullptr,
        WTbf, nullptr, 416, b_bond_final, nullptr, nullptr, nullptr, nullptr, out_bond, nullptr, NE);
    mgemm<256, 0, 0, -1, -1, 2><<<gNfull, 512, 0, stream>>>(
        node, FN, MN, DD, nullptr, 0, nullptr, 0, nullptr, nullptr,
        WTnf, nullptr, 416, b_node_final, nullptr, nullptr, nullptr, nullptr, out_node, nullptr, NN);
}

// Round 5
// 7735.649 us; speedup vs baseline: 3.5610x; 2.2175x over previous
//
#include <hip/hip_runtime.h>
#include <hip/hip_bf16.h>

#define NN 100000   // nodes
#define NE 200000   // bonds
#define NB 600000   // bond neighbours
#define FN 133
#define FB 14
#define FIB 147     // FN+FB
#define DD 256

typedef __hip_bfloat16 bf16;
typedef __attribute__((ext_vector_type(8))) short short8;   // 8 bf16 = 4 VGPR
typedef __attribute__((ext_vector_type(4))) float f32x4;

__device__ __forceinline__ float hswish(float x) {
    float c = fminf(fmaxf(x + 3.f, 0.f), 6.f);
    return x * c * (1.f / 6.f);
}
__device__ __forceinline__ float sigmoidf(float x) {
    return 1.f / (1.f + __expf(-x));
}
__device__ __forceinline__ float bf2f(unsigned short u) {
    union { unsigned int i; float f; } c; c.i = (unsigned int)u << 16; return c.f;
}
__device__ __forceinline__ unsigned short f2bf(float v) {
    bf16 b = __float2bfloat16(v);
    unsigned short u; __builtin_memcpy(&u, &b, 2); return u;
}

// ---------------- fill (zero counts + ws-guard sentinel) ----------------
__global__ __launch_bounds__(256) void fill_kernel(float* __restrict__ p, float v, long n4) {
    long i = (long)blockIdx.x * 256 + threadIdx.x;
    long st = (long)gridDim.x * 256;
    float4 z = {v, v, v, v};
    for (; i < n4; i += st) ((float4*)p)[i] = z;
}

// ---------------- CSR build helpers -------------------------------------
__global__ __launch_bounds__(256) void count_kernel(
    const int* __restrict__ idx, int n, int* __restrict__ cnt)
{
    int i = blockIdx.x * 256 + threadIdx.x;
    if (i < n) atomicAdd(&cnt[idx[i]], 1);
}

// per-1024-element block exclusive scan (in place), block totals -> bsum
__global__ __launch_bounds__(256) void scan_block(int* __restrict__ data, int* __restrict__ bsum)
{
    __shared__ int lds[256];
    int base = blockIdx.x * 1024 + threadIdx.x * 4;
    int c0 = data[base], c1 = data[base + 1], c2 = data[base + 2], c3 = data[base + 3];
    int t = c0 + c1 + c2 + c3;
    lds[threadIdx.x] = t;
    __syncthreads();
    int x = t;
    for (int off = 1; off < 256; off <<= 1) {
        int y = (threadIdx.x >= off) ? lds[threadIdx.x - off] : 0;
        __syncthreads();
        x += y; lds[threadIdx.x] = x;
        __syncthreads();
    }
    int excl = x - t;
    data[base] = excl; data[base + 1] = excl + c0;
    data[base + 2] = excl + c0 + c1; data[base + 3] = excl + c0 + c1 + c2;
    if (threadIdx.x == 255) bsum[blockIdx.x] = x;
}

// exclusive scan of <=256 block sums, single block
__global__ __launch_bounds__(256) void scan_bsum(int* __restrict__ bsum, int n)
{
    __shared__ int lds[256];
    int t = (threadIdx.x < n) ? bsum[threadIdx.x] : 0;
    lds[threadIdx.x] = t;
    __syncthreads();
    int x = t;
    for (int off = 1; off < 256; off <<= 1) {
        int y = (threadIdx.x >= off) ? lds[threadIdx.x - off] : 0;
        __syncthreads();
        x += y; lds[threadIdx.x] = x;
        __syncthreads();
    }
    if (threadIdx.x < n) bsum[threadIdx.x] = x - t;
}

__global__ __launch_bounds__(256) void scan_add(
    int* __restrict__ data, const int* __restrict__ bsum, int n)
{
    int i = blockIdx.x * 256 + threadIdx.x;
    if (i < n) data[i] += bsum[i >> 10];
}

__global__ __launch_bounds__(256) void copy_int(
    int* __restrict__ dst, const int* __restrict__ src, int n)
{
    int i = blockIdx.x * 256 + threadIdx.x;
    if (i < n) dst[i] = src[i];
}

__global__ __launch_bounds__(256) void fill_nb_list(
    const int* __restrict__ ij, const int* __restrict__ ki,
    int* __restrict__ cur, int* __restrict__ lst)
{
    int e = blockIdx.x * 256 + threadIdx.x;
    if (e < NB) { int p = atomicAdd(&cur[ij[e]], 1); lst[p] = ki[e]; }
}

__global__ __launch_bounds__(256) void fill_agg_list(
    const int* __restrict__ jidx, int* __restrict__ cur, int* __restrict__ lst)
{
    int e = blockIdx.x * 256 + threadIdx.x;
    if (e < NE) { int p = atomicAdd(&cur[jidx[e]], 1); lst[p] = e; }
}

// ---------------- CSR segment sums (one wave per segment, no atomics) ---
// S[sid] = sum over MB rows in lst[off[sid]..off[sid+1])
__global__ __launch_bounds__(256) void seg_s_kernel(
    const bf16* __restrict__ MB, const int* __restrict__ off,
    const int* __restrict__ lst, bf16* __restrict__ S, int nseg)
{
    int sid = blockIdx.x * 4 + (threadIdx.x >> 6);
    if (sid >= nseg) return;
    int lane = threadIdx.x & 63;
    int b = off[sid], e = off[sid + 1];
    float a0 = 0, a1 = 0, a2 = 0, a3 = 0;
    for (int t = b; t < e; t++) {
        int src = lst[t];
        ushort4 u = *(const ushort4*)((const unsigned short*)MB + (size_t)src * DD + lane * 4);
        a0 += bf2f(u.x); a1 += bf2f(u.y); a2 += bf2f(u.z); a3 += bf2f(u.w);
    }
    ushort4 o = {f2bf(a0), f2bf(a1), f2bf(a2), f2bf(a3)};
    *(ushort4*)((unsigned short*)S + (size_t)sid * DD + lane * 4) = o;
}

// R[sid] = sum sigmoid(PR[sid] + TR[src]) * MB[src]
__global__ __launch_bounds__(256) void seg_r_kernel(
    const bf16* __restrict__ MB, const bf16* __restrict__ TR,
    const bf16* __restrict__ PR, const int* __restrict__ off,
    const int* __restrict__ lst, bf16* __restrict__ R)
{
    int sid = blockIdx.x * 4 + (threadIdx.x >> 6);
    if (sid >= NE) return;
    int lane = threadIdx.x & 63;
    ushort4 up = *(const ushort4*)((const unsigned short*)PR + (size_t)sid * DD + lane * 4);
    float p0 = bf2f(up.x), p1 = bf2f(up.y), p2 = bf2f(up.z), p3 = bf2f(up.w);
    int b = off[sid], e = off[sid + 1];
    float a0 = 0, a1 = 0, a2 = 0, a3 = 0;
    for (int t = b; t < e; t++) {
        int src = lst[t];
        ushort4 ut = *(const ushort4*)((const unsigned short*)TR + (size_t)src * DD + lane * 4);
        ushort4 um = *(const ushort4*)((const unsigned short*)MB + (size_t)src * DD + lane * 4);
        a0 += sigmoidf(p0 + bf2f(ut.x)) * bf2f(um.x);
        a1 += sigmoidf(p1 + bf2f(ut.y)) * bf2f(um.y);
        a2 += sigmoidf(p2 + bf2f(ut.z)) * bf2f(um.z);
        a3 += sigmoidf(p3 + bf2f(ut.w)) * bf2f(um.w);
    }
    ushort4 o = {f2bf(a0), f2bf(a1), f2bf(a2), f2bf(a3)};
    *(ushort4*)((unsigned short*)R + (size_t)sid * DD + lane * 4) = o;
}

// ------------- weight pack: dst[n][k] = bf16(seg(k, n)), K-padded -------
__global__ __launch_bounds__(256) void pack_wt(
    const float* W1, int K1, const float* W2, int K2, const float* W3, int K3,
    int KTpad, bf16* dst)
{
    int idx = blockIdx.x * 256 + threadIdx.x;
    if (idx >= 256 * KTpad) return;
    int n = idx / KTpad, k = idx % KTpad;
    float v = 0.f;
    if (k < K1)                { if (W1) v = W1[(size_t)k * DD + n]; }
    else if (k < K1 + K2)      { if (W2) v = W2[(size_t)(k - K1) * DD + n]; }
    else if (k < K1 + K2 + K3) { if (W3) v = W3[(size_t)(k - K1 - K2) * DD + n]; }
    dst[(size_t)n * KTpad + k] = __float2bfloat16(v);
}

// segment element load. T: -1 unused, 0 f32, 1 bf16, 2 f32-gather, 3 bf16-gather
template <int T>
__device__ __forceinline__ float ldA(const void* p, int K, int mg, int mloc,
                                     const int* lidx, int k) {
    if constexpr (T < 0) { return 0.f; }
    else {
        int r = (T >= 2) ? lidx[mloc] : mg;
        if constexpr (T == 0 || T == 2) return ((const float*)p)[(size_t)r * K + k];
        else return __bfloat162float(((const bf16*)p)[(size_t)r * K + k]);
    }
}

// ---------------- MFMA GEMM, BM=128 x BN, K-step 32 ---------------------
// EP: 0 lin->bf16, 1 hsw->bf16, 2 hsw->f32, 3 blend (dual-W) -> bf16
template <int BN, int T1, int T2, int T3, int T4, int EP>
__global__ __launch_bounds__(BN == 256 ? 512 : 256) void mgemm(
    const void* __restrict__ p1, int K1, const void* __restrict__ p2, int K2,
    const void* __restrict__ p3, int K3, const void* __restrict__ p4, int K4,
    const int* __restrict__ gidx,
    const bf16* __restrict__ WT1, const bf16* __restrict__ WT2, int KTpad,
    const float* __restrict__ bias1, const float* __restrict__ bias2,
    const bf16* __restrict__ Sb,
    void* __restrict__ outp, int M)
{
    constexpr int BM = 128;
    constexpr int NT = (BN == 256) ? 512 : 256;
    constexpr int nWc = BN / 64;
    const int KT = K1 + K2 + K3 + K4;
    __shared__ __align__(16) unsigned short As[BM * 40];
    __shared__ __align__(16) unsigned short Bs[BN * 40];
    __shared__ __align__(16) unsigned short Bs2[(EP == 3 ? BN : 8) * 40];
    __shared__ int lidx[BM];
    const int tid = threadIdx.x;
    const int row0 = blockIdx.x * BM, col0 = blockIdx.y * BN;
    constexpr bool G = (T1 >= 2) || (T2 >= 2) || (T3 >= 2) || (T4 >= 2);
    if (G && tid < BM) { int m = row0 + tid; lidx[tid] = (m < M) ? gidx[m] : 0; }
    __syncthreads();

    f32x4 acc[4][4] = {};
    f32x4 acc2[4][4] = {};
    const int lane = tid & 63, w = tid >> 6;
    const int wr = w / nWc, wc = w % nWc;
    const int fr = lane & 15, ko = (lane >> 4) * 8;

    for (int k0 = 0; k0 < KTpad; k0 += 32) {
        // ---- A stage: 128x32 bf16, stride-40 padded rows
        #pragma unroll
        for (int it = 0; it < BM / (NT / 4); ++it) {
            int mloc = (tid >> 2) + it * (NT / 4);
            int mg = row0 + mloc;
            int kq = (tid & 3) * 8;
            unsigned short us[8];
            #pragma unroll
            for (int j = 0; j < 8; j++) {
                int kg = k0 + kq + j;
                float v = 0.f;
                if (mg < M && kg < KT) {
                    if (kg < K1)                v = ldA<T1>(p1, K1, mg, mloc, lidx, kg);
                    else if (kg < K1 + K2)      v = ldA<T2>(p2, K2, mg, mloc, lidx, kg - K1);
                    else if (kg < K1 + K2 + K3) v = ldA<T3>(p3, K3, mg, mloc, lidx, kg - K1 - K2);
                    else                        v = ldA<T4>(p4, K4, mg, mloc, lidx, kg - K1 - K2 - K3);
                }
                us[j] = f2bf(v);
            }
            uint4 pk;
            pk.x = us[0] | ((unsigned)us[1] << 16); pk.y = us[2] | ((unsigned)us[3] << 16);
            pk.z = us[4] | ((unsigned)us[5] << 16); pk.w = us[6] | ((unsigned)us[7] << 16);
            *(uint4*)&As[mloc * 40 + kq] = pk;
        }
        // ---- B stage: WT[n][k] bf16 (pre-packed, aligned) -> Bs[n][k]
        #pragma unroll
        for (int it = 0; it < BN / (NT / 4); ++it) {
            int nloc = (tid >> 2) + it * (NT / 4);
            int kq = (tid & 3) * 8;
            *(uint4*)&Bs[nloc * 40 + kq] =
                *(const uint4*)&WT1[(size_t)(col0 + nloc) * KTpad + k0 + kq];
            if (EP == 3)
                *(uint4*)&Bs2[nloc * 40 + kq] =
                    *(const uint4*)&WT2[(size_t)(col0 + nloc) * KTpad + k0 + kq];
        }
        __syncthreads();
        short8 a[4], b[4], b2[4];
        #pragma unroll
        for (int m = 0; m < 4; m++)
            a[m] = *(const short8*)&As[(wr * 64 + m * 16 + fr) * 40 + ko];
        #pragma unroll
        for (int n = 0; n < 4; n++) {
            b[n] = *(const short8*)&Bs[(wc * 64 + n * 16 + fr) * 40 + ko];
            if (EP == 3)
                b2[n] = *(const short8*)&Bs2[(wc * 64 + n * 16 + fr) * 40 + ko];
        }
        #pragma unroll
        for (int m = 0; m < 4; m++)
            #pragma unroll
            for (int n = 0; n < 4; n++) {
                acc[m][n] = __builtin_amdgcn_mfma_f32_16x16x32_bf16(a[m], b[n], acc[m][n], 0, 0, 0);
                if (EP == 3)
                    acc2[m][n] = __builtin_amdgcn_mfma_f32_16x16x32_bf16(a[m], b2[n], acc2[m][n], 0, 0, 0);
            }
        __syncthreads();
    }

    // ---- epilogue. D layout: col = lane&15, row = (lane>>4)*4 + i
    #pragma unroll
    for (int m = 0; m < 4; m++) {
        #pragma unroll
        for (int i = 0; i < 4; i++) {
            int mloc = wr * 64 + m * 16 + (lane >> 4) * 4 + i;
            int gm = row0 + mloc;
            if (gm >= M) continue;
            #pragma unroll
            for (int n = 0; n < 4; n++) {
                int gc = col0 + wc * 64 + n * 16 + (lane & 15);
                float v = acc[m][n][i];
                if (EP == 3) {
                    float z  = sigmoidf(v + bias1[gc]);
                    float mm = tanhf(acc2[m][n][i] + bias2[gc]);
                    float s  = __bfloat162float(Sb[(size_t)gm * DD + gc]);
                    ((bf16*)outp)[(size_t)gm * DD + gc] =
                        __float2bfloat16((1.f - z) * s + z * mm);
                } else {
                    if (bias1) v += bias1[gc];
                    if (EP != 0) v = hswish(v);
                    if (EP == 2) ((float*)outp)[(size_t)gm * DD + gc] = v;
                    else         ((bf16*)outp)[(size_t)gm * DD + gc] = __float2bfloat16(v);
                }
            }
        }
    }
}

extern "C" void kernel_launch(void* const* d_in, const int* in_sizes, int n_in,
                              void* d_out, int out_size, void* d_ws, size_t ws_size,
                              hipStream_t stream)
{
    const float* node  = (const float*)d_in[0];
    const float* bond  = (const float*)d_in[1];
    const int* connect = (const int*)d_in[2];
    const int* bnb     = (const int*)d_in[3];
    const float* w_node       = (const float*)d_in[4];
    const float* b_node       = (const float*)d_in[5];
    const float* w_node_final = (const float*)d_in[6];
    const float* b_node_final = (const float*)d_in[7];
    const float* w_bond       = (const float*)d_in[8];
    const float* b_bond       = (const float*)d_in[9];
    const float* w_bond_final = (const float*)d_in[10];
    const float* b_bond_final = (const float*)d_in[11];
    const float* w_z = (const float*)d_in[12];
    const float* b_z = (const float*)d_in[13];
    const float* w_r = (const float*)d_in[14];
    const float* b_r = (const float*)d_in[15];
    const float* u_  = (const float*)d_in[16];
    const float* w_m = (const float*)d_in[17];
    const float* b_m = (const float*)d_in[18];
    const float* w_n = (const float*)d_in[19];
    const float* b_n = (const float*)d_in[20];
    const float* u_n = (const float*)d_in[21];

    const int* i_idx = connect;            // connect[0]
    const int* j_idx = connect + NE;       // connect[1]
    const int* ij    = bnb;                // bond_neighbour[0]
    const int* ki    = bnb + NB;           // bond_neighbour[1]

    // ---- workspace layout ----
    const size_t B_PR = (size_t)NE * DD * 2;       // 102,400,000
    const size_t B_MB = (size_t)NE * DD * 2;       // 102,400,000
    const size_t B_TR = (size_t)NE * DD * 2;       // 102,400,000 (AGG aliases)
    const size_t B_WT = 1835008;
    const int NEpad = 196 * 1024;                  // 200704
    const int NNpad = 98 * 1024;                   // 100352
    const size_t B_CSR = (size_t)NEpad * 4 * 2 + (size_t)NB * 4
                       + (size_t)NNpad * 4 * 2 + (size_t)NE * 4 + 2048;
    const size_t NEED = B_PR + B_MB + B_TR + B_WT + B_CSR;   // ~315 MB

    float* out_node = (float*)d_out;               // MN lives here (f32)
    float* out_bond = out_node + (size_t)NN * DD;  // R,S (bf16) live here

    if (ws_size < NEED) {   // diagnostic sentinel
        fill_kernel<<<2048, 256, 0, stream>>>((float*)d_out, 1e6f, (long)out_size / 4);
        return;
    }

    char* base = (char*)d_ws;
    bf16* PR = (bf16*)base;                       base += B_PR;
    bf16* MB = (bf16*)base;                       base += B_MB;
    bf16* TR = (bf16*)base;                       base += B_TR;
    bf16* AGG = TR;                                // TR dead when AGG live
    char* wt = base;                              base += B_WT;
    int* offE  = (int*)base;                      base += (size_t)NEpad * 4;
    int* curE  = (int*)base;                      base += (size_t)NEpad * 4;
    int* nbLst = (int*)base;                      base += (size_t)NB * 4;
    int* offN  = (int*)base;                      base += (size_t)NNpad * 4;
    int* curN  = (int*)base;                      base += (size_t)NNpad * 4;
    int* agLst = (int*)base;                      base += (size_t)NE * 4;
    int* bsumE = (int*)base;                      base += 1024;
    int* bsumN = (int*)base;

    bf16* R = (bf16*)out_bond;                       // 102.4 MB
    bf16* S = R + (size_t)NE * DD;                   // 102.4 MB
    float* MN = out_node;

    auto wtAlloc = [&](size_t elems) { bf16* p = (bf16*)wt; wt += elems * 2; return p; };
    bf16* WTz  = wtAlloc(672 * 256);   // w_z(403) over [node|bond|S], zeros for R
    bf16* WTm  = wtAlloc(672 * 256);   // w_m(147) | zeros(256) | u(256)
    bf16* WTnu = wtAlloc(672 * 256);   // w_n(133) | u_n(512)
    bf16* WTr2 = wtAlloc(256 * 256);   // w_r rows 147..402
    bf16* WTr  = wtAlloc(160 * 256);   // w_r rows 0..146
    bf16* WTb  = wtAlloc(160 * 256);   // w_bond(147)
    bf16* WTn0 = wtAlloc(160 * 256);   // w_node(133)
    bf16* WTbf = wtAlloc(416 * 256);   // w_bond_final(403)
    bf16* WTnf = wtAlloc(416 * 256);   // w_node_final(389)

    const float* w_r2 = w_r + (size_t)FIB * DD;

    auto packG = [&](int ktpad) { return (256 * ktpad + 255) / 256; };
    pack_wt<<<packG(672), 256, 0, stream>>>(w_z, 403, nullptr, 0, nullptr, 0, 672, WTz);
    pack_wt<<<packG(672), 256, 0, stream>>>(w_m, FIB, nullptr, DD, u_, DD, 672, WTm);
    pack_wt<<<packG(672), 256, 0, stream>>>(w_n, FN, u_n, 2 * DD, nullptr, 0, 672, WTnu);
    pack_wt<<<packG(256), 256, 0, stream>>>(w_r2, DD, nullptr, 0, nullptr, 0, 256, WTr2);
    pack_wt<<<packG(160), 256, 0, stream>>>(w_r, FIB, nullptr, 0, nullptr, 0, 160, WTr);
    pack_wt<<<packG(160), 256, 0, stream>>>(w_bond, FIB, nullptr, 0, nullptr, 0, 160, WTb);
    pack_wt<<<packG(160), 256, 0, stream>>>(w_node, FN, nullptr, 0, nullptr, 0, 160, WTn0);
    pack_wt<<<packG(416), 256, 0, stream>>>(w_bond_final, 403, nullptr, 0, nullptr, 0, 416, WTbf);
    pack_wt<<<packG(416), 256, 0, stream>>>(w_node_final, 389, nullptr, 0, nullptr, 0, 416, WTnf);

    // ---- CSR build (layer-invariant) ----
    fill_kernel<<<256, 256, 0, stream>>>((float*)offE, 0.f, NEpad / 4);
    fill_kernel<<<256, 256, 0, stream>>>((float*)offN, 0.f, NNpad / 4);
    count_kernel<<<(NB + 255) / 256, 256, 0, stream>>>(ij, NB, offE);
    count_kernel<<<(NE + 255) / 256, 256, 0, stream>>>(j_idx, NE, offN);
    scan_block<<<196, 256, 0, stream>>>(offE, bsumE);
    scan_bsum<<<1, 256, 0, stream>>>(bsumE, 196);
    scan_add<<<NEpad / 256, 256, 0, stream>>>(offE, bsumE, NEpad);
    scan_block<<<98, 256, 0, stream>>>(offN, bsumN);
    scan_bsum<<<1, 256, 0, stream>>>(bsumN, 98);
    scan_add<<<NNpad / 256, 256, 0, stream>>>(offN, bsumN, NNpad);
    copy_int<<<NEpad / 256, 256, 0, stream>>>(curE, offE, NEpad);
    copy_int<<<NNpad / 256, 256, 0, stream>>>(curN, offN, NNpad);
    fill_nb_list<<<(NB + 255) / 256, 256, 0, stream>>>(ij, ki, curE, nbLst);
    fill_agg_list<<<(NE + 255) / 256, 256, 0, stream>>>(j_idx, curN, agLst);

    dim3 gB((NE + 127) / 128, 2);     // 1563 x 2
    dim3 gN((NN + 127) / 128, 2);     // 782 x 2
    dim3 gNfull((NN + 127) / 128, 1); // 782, BN=256

    // hoisted, layer-invariant
    mgemm<128, 0, -1, -1, -1, 2><<<gN, 256, 0, stream>>>(
        node, FN, nullptr, 0, nullptr, 0, nullptr, 0, nullptr,
        WTn0, nullptr, 160, b_node, nullptr, nullptr, MN, NN);
    mgemm<128, 2, 0, -1, -1, 0><<<gB, 256, 0, stream>>>(
        node, FN, bond, FB, nullptr, 0, nullptr, 0, i_idx,
        WTr, nullptr, 160, b_r, nullptr, nullptr, PR, NE);
    mgemm<128, 2, 0, -1, -1, 1><<<gB, 256, 0, stream>>>(
        node, FN, bond, FB, nullptr, 0, nullptr, 0, i_idx,
        WTb, nullptr, 160, b_bond, nullptr, nullptr, MB, NE);

    for (int l = 0; l < 3; l++) {
        seg_s_kernel<<<(NE + 3) / 4, 256, 0, stream>>>(MB, offE, nbLst, S, NE);
        mgemm<128, 1, -1, -1, -1, 0><<<gB, 256, 0, stream>>>(
            MB, DD, nullptr, 0, nullptr, 0, nullptr, 0, nullptr,
            WTr2, nullptr, 256, nullptr, nullptr, nullptr, TR, NE);
        seg_r_kernel<<<(NE + 3) / 4, 256, 0, stream>>>(MB, TR, PR, offE, nbLst, R);
        mgemm<128, 2, 0, 1, 1, 3><<<gB, 256, 0, stream>>>(
            node, FN, bond, FB, S, DD, R, DD, i_idx,
            WTz, WTm, 672, b_z, b_m, S, MB, NE);
        seg_s_kernel<<<(NN + 3) / 4, 256, 0, stream>>>(MB, offN, agLst, AGG, NN);
        mgemm<256, 0, 0, 1, -1, 2><<<gNfull, 512, 0, stream>>>(
            node, FN, MN, DD, AGG, DD, nullptr, 0, nullptr,
            WTnu, nullptr, 672, b_n, nullptr, nullptr, MN, NN);
    }

    mgemm<128, 2, 0, 1, -1, 2><<<gB, 256, 0, stream>>>(
        node, FN, bond, FB, MB, DD, nullptr, 0, i_idx,
        WTbf, nullptr, 416, b_bond_final, nullptr, nullptr, out_bond, NE);
    mgemm<256, 0, 0, -1, -1, 2><<<gNfull, 512, 0, stream>>>(
        node, FN, MN, DD, nullptr, 0, nullptr, 0, nullptr,
        WTnf, nullptr, 416, b_node_final, nullptr, nullptr, out_node, NN);
}

// Round 6
// 4243.341 us; speedup vs baseline: 6.4918x; 1.8230x over previous
//
#include <hip/hip_runtime.h>
#include <hip/hip_bf16.h>

#define NN 100000   // nodes
#define NE 200000   // bonds
#define NB 600000   // bond neighbours
#define FN 133
#define FB 14
#define FIB 147     // FN+FB
#define DD 256

typedef __hip_bfloat16 bf16;
typedef __attribute__((ext_vector_type(8))) short short8;   // 8 bf16 = 4 VGPR
typedef __attribute__((ext_vector_type(4))) float f32x4;

__device__ __forceinline__ float hswish(float x) {
    float c = fminf(fmaxf(x + 3.f, 0.f), 6.f);
    return x * c * (1.f / 6.f);
}
__device__ __forceinline__ float sigmoidf(float x) {
    return 1.f / (1.f + __expf(-x));
}
__device__ __forceinline__ float bf2f(unsigned short u) {
    union { unsigned int i; float f; } c; c.i = (unsigned int)u << 16; return c.f;
}
__device__ __forceinline__ unsigned short f2bf(float v) {
    bf16 b = __float2bfloat16(v);
    unsigned short u; __builtin_memcpy(&u, &b, 2); return u;
}

// ---------------- fill (zero counts + ws-guard sentinel) ----------------
__global__ __launch_bounds__(256) void fill_kernel(float* __restrict__ p, float v, long n4) {
    long i = (long)blockIdx.x * 256 + threadIdx.x;
    long st = (long)gridDim.x * 256;
    float4 z = {v, v, v, v};
    for (; i < n4; i += st) ((float4*)p)[i] = z;
}

// ---------------- CSR build helpers -------------------------------------
__global__ __launch_bounds__(256) void count_kernel(
    const int* __restrict__ idx, int n, int* __restrict__ cnt)
{
    int i = blockIdx.x * 256 + threadIdx.x;
    if (i < n) atomicAdd(&cnt[idx[i]], 1);
}

__global__ __launch_bounds__(256) void scan_block(int* __restrict__ data, int* __restrict__ bsum)
{
    __shared__ int lds[256];
    int base = blockIdx.x * 1024 + threadIdx.x * 4;
    int c0 = data[base], c1 = data[base + 1], c2 = data[base + 2], c3 = data[base + 3];
    int t = c0 + c1 + c2 + c3;
    lds[threadIdx.x] = t;
    __syncthreads();
    int x = t;
    for (int off = 1; off < 256; off <<= 1) {
        int y = (threadIdx.x >= off) ? lds[threadIdx.x - off] : 0;
        __syncthreads();
        x += y; lds[threadIdx.x] = x;
        __syncthreads();
    }
    int excl = x - t;
    data[base] = excl; data[base + 1] = excl + c0;
    data[base + 2] = excl + c0 + c1; data[base + 3] = excl + c0 + c1 + c2;
    if (threadIdx.x == 255) bsum[blockIdx.x] = x;
}

__global__ __launch_bounds__(256) void scan_bsum(int* __restrict__ bsum, int n)
{
    __shared__ int lds[256];
    int t = (threadIdx.x < n) ? bsum[threadIdx.x] : 0;
    lds[threadIdx.x] = t;
    __syncthreads();
    int x = t;
    for (int off = 1; off < 256; off <<= 1) {
        int y = (threadIdx.x >= off) ? lds[threadIdx.x - off] : 0;
        __syncthreads();
        x += y; lds[threadIdx.x] = x;
        __syncthreads();
    }
    if (threadIdx.x < n) bsum[threadIdx.x] = x - t;
}

__global__ __launch_bounds__(256) void scan_add(
    int* __restrict__ data, const int* __restrict__ bsum, int n)
{
    int i = blockIdx.x * 256 + threadIdx.x;
    if (i < n) data[i] += bsum[i >> 10];
}

__global__ __launch_bounds__(256) void copy_int(
    int* __restrict__ dst, const int* __restrict__ src, int n)
{
    int i = blockIdx.x * 256 + threadIdx.x;
    if (i < n) dst[i] = src[i];
}

__global__ __launch_bounds__(256) void fill_nb_list(
    const int* __restrict__ ij, const int* __restrict__ ki,
    int* __restrict__ cur, int* __restrict__ lst)
{
    int e = blockIdx.x * 256 + threadIdx.x;
    if (e < NB) { int p = atomicAdd(&cur[ij[e]], 1); lst[p] = ki[e]; }
}

__global__ __launch_bounds__(256) void fill_agg_list(
    const int* __restrict__ jidx, int* __restrict__ cur, int* __restrict__ lst)
{
    int e = blockIdx.x * 256 + threadIdx.x;
    if (e < NE) { int p = atomicAdd(&cur[jidx[e]], 1); lst[p] = e; }
}

// ---------------- CSR segment sums (one wave per segment, no atomics) ---
__global__ __launch_bounds__(256) void seg_s_kernel(
    const bf16* __restrict__ MB, const int* __restrict__ off,
    const int* __restrict__ lst, bf16* __restrict__ S, int nseg)
{
    int sid = blockIdx.x * 4 + (threadIdx.x >> 6);
    if (sid >= nseg) return;
    int lane = threadIdx.x & 63;
    int b = off[sid], e = off[sid + 1];
    float a0 = 0, a1 = 0, a2 = 0, a3 = 0;
    for (int t = b; t < e; t++) {
        int src = lst[t];
        ushort4 u = *(const ushort4*)((const unsigned short*)MB + (size_t)src * DD + lane * 4);
        a0 += bf2f(u.x); a1 += bf2f(u.y); a2 += bf2f(u.z); a3 += bf2f(u.w);
    }
    ushort4 o = {f2bf(a0), f2bf(a1), f2bf(a2), f2bf(a3)};
    *(ushort4*)((unsigned short*)S + (size_t)sid * DD + lane * 4) = o;
}

__global__ __launch_bounds__(256) void seg_r_kernel(
    const bf16* __restrict__ MB, const bf16* __restrict__ TR,
    const bf16* __restrict__ PR, const int* __restrict__ off,
    const int* __restrict__ lst, bf16* __restrict__ R)
{
    int sid = blockIdx.x * 4 + (threadIdx.x >> 6);
    if (sid >= NE) return;
    int lane = threadIdx.x & 63;
    ushort4 up = *(const ushort4*)((const unsigned short*)PR + (size_t)sid * DD + lane * 4);
    float p0 = bf2f(up.x), p1 = bf2f(up.y), p2 = bf2f(up.z), p3 = bf2f(up.w);
    int b = off[sid], e = off[sid + 1];
    float a0 = 0, a1 = 0, a2 = 0, a3 = 0;
    for (int t = b; t < e; t++) {
        int src = lst[t];
        ushort4 ut = *(const ushort4*)((const unsigned short*)TR + (size_t)src * DD + lane * 4);
        ushort4 um = *(const ushort4*)((const unsigned short*)MB + (size_t)src * DD + lane * 4);
        a0 += sigmoidf(p0 + bf2f(ut.x)) * bf2f(um.x);
        a1 += sigmoidf(p1 + bf2f(ut.y)) * bf2f(um.y);
        a2 += sigmoidf(p2 + bf2f(ut.z)) * bf2f(um.z);
        a3 += sigmoidf(p3 + bf2f(ut.w)) * bf2f(um.w);
    }
    ushort4 o = {f2bf(a0), f2bf(a1), f2bf(a2), f2bf(a3)};
    *(ushort4*)((unsigned short*)R + (size_t)sid * DD + lane * 4) = o;
}

// ------------- weight pack: dst[n][k] = bf16(seg(k, n)), K-padded -------
__global__ __launch_bounds__(256) void pack_wt(
    const float* W1, int K1, const float* W2, int K2, const float* W3, int K3,
    int KTpad, bf16* dst)
{
    int idx = blockIdx.x * 256 + threadIdx.x;
    if (idx >= 256 * KTpad) return;
    int n = idx / KTpad, k = idx % KTpad;
    float v = 0.f;
    if (k < K1)                { if (W1) v = W1[(size_t)k * DD + n]; }
    else if (k < K1 + K2)      { if (W2) v = W2[(size_t)(k - K1) * DD + n]; }
    else if (k < K1 + K2 + K3) { if (W3) v = W3[(size_t)(k - K1 - K2) * DD + n]; }
    dst[(size_t)n * KTpad + k] = __float2bfloat16(v);
}

// T: -1 unused, 0 f32, 1 bf16, 2 f32-gather, 3 bf16-gather
template <int T>
__device__ __forceinline__ float ldA(const void* p, int K, int mg, int mloc,
                                     const int* lidx, int k) {
    if constexpr (T < 0) { return 0.f; }
    else {
        int r = (T >= 2) ? lidx[mloc] : mg;
        if constexpr (T == 0 || T == 2) return ((const float*)p)[(size_t)r * K + k];
        else return __bfloat162float(((const bf16*)p)[(size_t)r * K + k]);
    }
}

// ---------------- general MFMA GEMM (mixed dtypes / gather A) -----------
// EP: 0 lin->bf16, 1 hsw->bf16, 2 hsw->f32, 3 blend(dual)->bf16,
//     4 dual lin -> two bf16 outputs (outp, outp2)
template <int BN, int T1, int T2, int T3, int T4, int EP>
__global__ __launch_bounds__(BN == 256 ? 512 : 256) void mgemm(
    const void* __restrict__ p1, int K1, const void* __restrict__ p2, int K2,
    const void* __restrict__ p3, int K3, const void* __restrict__ p4, int K4,
    const int* __restrict__ gidx,
    const bf16* __restrict__ WT1, const bf16* __restrict__ WT2, int KTpad,
    const float* __restrict__ bias1, const float* __restrict__ bias2,
    const bf16* __restrict__ Sb,
    void* __restrict__ outp, void* __restrict__ outp2, int M)
{
    constexpr int BM = 128;
    constexpr int NT = (BN == 256) ? 512 : 256;
    constexpr int nWc = BN / 64;
    constexpr bool DW = (EP == 3 || EP == 4);
    const int KT = K1 + K2 + K3 + K4;
    __shared__ __align__(16) unsigned short As[BM * 40];
    __shared__ __align__(16) unsigned short Bs[BN * 40];
    __shared__ __align__(16) unsigned short Bs2[(DW ? BN : 8) * 40];
    __shared__ int lidx[BM];
    const int tid = threadIdx.x;
    const int row0 = blockIdx.x * BM, col0 = blockIdx.y * BN;
    constexpr bool G = (T1 >= 2) || (T2 >= 2) || (T3 >= 2) || (T4 >= 2);
    if (G && tid < BM) { int m = row0 + tid; lidx[tid] = (m < M) ? gidx[m] : 0; }
    __syncthreads();

    f32x4 acc[4][4] = {};
    f32x4 acc2[4][4] = {};
    const int lane = tid & 63, w = tid >> 6;
    const int wr = w / nWc, wc = w % nWc;
    const int fr = lane & 15, ko = (lane >> 4) * 8;

    for (int k0 = 0; k0 < KTpad; k0 += 32) {
        #pragma unroll
        for (int it = 0; it < BM / (NT / 4); ++it) {
            int mloc = (tid >> 2) + it * (NT / 4);
            int mg = row0 + mloc;
            int kq = (tid & 3) * 8;
            unsigned short us[8];
            #pragma unroll
            for (int j = 0; j < 8; j++) {
                int kg = k0 + kq + j;
                float v = 0.f;
                if (mg < M && kg < KT) {
                    if (kg < K1)                v = ldA<T1>(p1, K1, mg, mloc, lidx, kg);
                    else if (kg < K1 + K2)      v = ldA<T2>(p2, K2, mg, mloc, lidx, kg - K1);
                    else if (kg < K1 + K2 + K3) v = ldA<T3>(p3, K3, mg, mloc, lidx, kg - K1 - K2);
                    else                        v = ldA<T4>(p4, K4, mg, mloc, lidx, kg - K1 - K2 - K3);
                }
                us[j] = f2bf(v);
            }
            uint4 pk;
            pk.x = us[0] | ((unsigned)us[1] << 16); pk.y = us[2] | ((unsigned)us[3] << 16);
            pk.z = us[4] | ((unsigned)us[5] << 16); pk.w = us[6] | ((unsigned)us[7] << 16);
            *(uint4*)&As[mloc * 40 + kq] = pk;
        }
        #pragma unroll
        for (int it = 0; it < BN / (NT / 4); ++it) {
            int nloc = (tid >> 2) + it * (NT / 4);
            int kq = (tid & 3) * 8;
            *(uint4*)&Bs[nloc * 40 + kq] =
                *(const uint4*)&WT1[(size_t)(col0 + nloc) * KTpad + k0 + kq];
            if (DW)
                *(uint4*)&Bs2[nloc * 40 + kq] =
                    *(const uint4*)&WT2[(size_t)(col0 + nloc) * KTpad + k0 + kq];
        }
        __syncthreads();
        short8 a[4], b[4], b2[4];
        #pragma unroll
        for (int m = 0; m < 4; m++)
            a[m] = *(const short8*)&As[(wr * 64 + m * 16 + fr) * 40 + ko];
        #pragma unroll
        for (int n = 0; n < 4; n++) {
            b[n] = *(const short8*)&Bs[(wc * 64 + n * 16 + fr) * 40 + ko];
            if (DW) b2[n] = *(const short8*)&Bs2[(wc * 64 + n * 16 + fr) * 40 + ko];
        }
        #pragma unroll
        for (int m = 0; m < 4; m++)
            #pragma unroll
            for (int n = 0; n < 4; n++) {
                acc[m][n] = __builtin_amdgcn_mfma_f32_16x16x32_bf16(a[m], b[n], acc[m][n], 0, 0, 0);
                if (DW)
                    acc2[m][n] = __builtin_amdgcn_mfma_f32_16x16x32_bf16(a[m], b2[n], acc2[m][n], 0, 0, 0);
            }
        __syncthreads();
    }

    #pragma unroll
    for (int m = 0; m < 4; m++) {
        #pragma unroll
        for (int i = 0; i < 4; i++) {
            int mloc = wr * 64 + m * 16 + (lane >> 4) * 4 + i;
            int gm = row0 + mloc;
            if (gm >= M) continue;
            #pragma unroll
            for (int n = 0; n < 4; n++) {
                int gc = col0 + wc * 64 + n * 16 + (lane & 15);
                size_t idx = (size_t)gm * DD + gc;
                float v = acc[m][n][i];
                if (EP == 3) {
                    float z  = sigmoidf(v + bias1[gc]);
                    float mm = tanhf(acc2[m][n][i] + bias2[gc]);
                    float s  = __bfloat162float(Sb[idx]);
                    ((bf16*)outp)[idx] = __float2bfloat16((1.f - z) * s + z * mm);
                } else if (EP == 4) {
                    ((bf16*)outp)[idx]  = __float2bfloat16(v + bias1[gc]);
                    ((bf16*)outp2)[idx] = __float2bfloat16(acc2[m][n][i] + bias2[gc]);
                } else {
                    if (bias1) v += bias1[gc];
                    if (EP != 0) v = hswish(v);
                    if (EP == 2) ((float*)outp)[idx] = v;
                    else         ((bf16*)outp)[idx] = __float2bfloat16(v);
                }
            }
        }
    }
}

// ---------------- all-bf16 MFMA GEMM (vector staging, no converts) ------
// DUAL: acc1 = A1@WT1, acc2 = A2@WT2 (each K=256, shared staging)
// else: acc = [A1|A2..]@WT1 (K = NSEG*256)
// EPB: 0 lin->bf16 ; 1 blend: out=(1-z)*A1+z*tanh(acc2+PM), z=sig(acc1+PZ)
//      2 hsw(acc + PX)->bf16 (node update; PX=PN)
template <int BN, int NSEG, int DUAL, int EPB>
__global__ __launch_bounds__((BN == 256 || DUAL) ? 512 : 256) void bgemm(
    const bf16* __restrict__ A1, const bf16* __restrict__ A2,
    const bf16* __restrict__ WT1, const bf16* __restrict__ WT2,
    const bf16* __restrict__ PZb, const bf16* __restrict__ PMb,
    bf16* __restrict__ outp, int M)
{
    constexpr int BM = 128;
    constexpr int NT = (BN == 256 || DUAL) ? 512 : 256;
    constexpr int nWc = BN / 64;
    constexpr int nWr = (NT / 64) / nWc;
    constexpr int MSPAN = BM / nWr;
    constexpr int MFR = MSPAN / 16;
    constexpr int KT = DUAL ? 256 : NSEG * 256;
    __shared__ __align__(16) unsigned short As[BM * 40];
    __shared__ __align__(16) unsigned short Bs[BN * 40];
    __shared__ __align__(16) unsigned short As2[(DUAL ? BM : 8) * 40];
    __shared__ __align__(16) unsigned short Bs2[(DUAL ? BN : 8) * 40];
    const int tid = threadIdx.x;
    const int row0 = blockIdx.x * BM, col0 = blockIdx.y * BN;
    const int lane = tid & 63, w = tid >> 6;
    const int wr = w / nWc, wc = w % nWc;
    const int fr = lane & 15, ko = (lane >> 4) * 8;

    f32x4 acc[MFR][4] = {};
    f32x4 acc2[DUAL ? MFR : 1][DUAL ? 4 : 1] = {};

    for (int k0 = 0; k0 < KT; k0 += 32) {
        #pragma unroll
        for (int it = 0; it < BM / (NT / 4); ++it) {
            int mloc = (tid >> 2) + it * (NT / 4);
            int mg = row0 + mloc;
            int kq = (tid & 3) * 8;
            uint4 zz = {0, 0, 0, 0};
            if (!DUAL) {
                int kg = k0 + kq;
                const bf16* seg = (NSEG == 2 && kg >= 256) ? A2 : A1;
                uint4 v = zz;
                if (mg < M) v = *(const uint4*)(seg + (size_t)mg * 256 + (kg & 255));
                *(uint4*)&As[mloc * 40 + kq] = v;
            } else {
                uint4 v1 = zz, v2 = zz;
                if (mg < M) {
                    v1 = *(const uint4*)(A1 + (size_t)mg * 256 + k0 + kq);
                    v2 = *(const uint4*)(A2 + (size_t)mg * 256 + k0 + kq);
                }
                *(uint4*)&As[mloc * 40 + kq] = v1;
                *(uint4*)&As2[mloc * 40 + kq] = v2;
            }
        }
        #pragma unroll
        for (int it = 0; it < BN / (NT / 4); ++it) {
            int nloc = (tid >> 2) + it * (NT / 4);
            int kq = (tid & 3) * 8;
            *(uint4*)&Bs[nloc * 40 + kq] =
                *(const uint4*)&WT1[(size_t)(col0 + nloc) * KT + k0 + kq];
            if (DUAL)
                *(uint4*)&Bs2[nloc * 40 + kq] =
                    *(const uint4*)&WT2[(size_t)(col0 + nloc) * KT + k0 + kq];
        }
        __syncthreads();
        short8 a1f[MFR], b1f[4], a2f[DUAL ? MFR : 1], b2f[DUAL ? 4 : 1];
        #pragma unroll
        for (int mf = 0; mf < MFR; mf++) {
            a1f[mf] = *(const short8*)&As[(wr * MSPAN + mf * 16 + fr) * 40 + ko];
            if (DUAL) a2f[mf] = *(const short8*)&As2[(wr * MSPAN + mf * 16 + fr) * 40 + ko];
        }
        #pragma unroll
        for (int nf = 0; nf < 4; nf++) {
            b1f[nf] = *(const short8*)&Bs[(wc * 64 + nf * 16 + fr) * 40 + ko];
            if (DUAL) b2f[nf] = *(const short8*)&Bs2[(wc * 64 + nf * 16 + fr) * 40 + ko];
        }
        #pragma unroll
        for (int mf = 0; mf < MFR; mf++)
            #pragma unroll
            for (int nf = 0; nf < 4; nf++) {
                acc[mf][nf] = __builtin_amdgcn_mfma_f32_16x16x32_bf16(a1f[mf], b1f[nf], acc[mf][nf], 0, 0, 0);
                if (DUAL)
                    acc2[mf][nf] = __builtin_amdgcn_mfma_f32_16x16x32_bf16(a2f[mf], b2f[nf], acc2[mf][nf], 0, 0, 0);
            }
        __syncthreads();
    }

    #pragma unroll
    for (int mf = 0; mf < MFR; mf++) {
        #pragma unroll
        for (int i = 0; i < 4; i++) {
            int mloc = wr * MSPAN + mf * 16 + (lane >> 4) * 4 + i;
            int gm = row0 + mloc;
            if (gm >= M) continue;
            #pragma unroll
            for (int nf = 0; nf < 4; nf++) {
                int gc = col0 + wc * 64 + nf * 16 + (lane & 15);
                size_t idx = (size_t)gm * DD + gc;
                float v = acc[mf][nf][i];
                if (EPB == 0) {
                    outp[idx] = __float2bfloat16(v);
                } else if (EPB == 1) {
                    float z  = sigmoidf(v + __bfloat162float(PZb[idx]));
                    float mm = tanhf(acc2[DUAL ? mf : 0][DUAL ? nf : 0][i]
                                     + __bfloat162float(PMb[idx]));
                    float s  = __bfloat162float(A1[idx]);
                    outp[idx] = __float2bfloat16((1.f - z) * s + z * mm);
                } else {
                    outp[idx] = __float2bfloat16(hswish(v + __bfloat162float(PZb[idx])));
                }
            }
        }
    }
}

extern "C" void kernel_launch(void* const* d_in, const int* in_sizes, int n_in,
                              void* d_out, int out_size, void* d_ws, size_t ws_size,
                              hipStream_t stream)
{
    const float* node  = (const float*)d_in[0];
    const float* bond  = (const float*)d_in[1];
    const int* connect = (const int*)d_in[2];
    const int* bnb     = (const int*)d_in[3];
    const float* w_node       = (const float*)d_in[4];
    const float* b_node       = (const float*)d_in[5];
    const float* w_node_final = (const float*)d_in[6];
    const float* b_node_final = (const float*)d_in[7];
    const float* w_bond       = (const float*)d_in[8];
    const float* b_bond       = (const float*)d_in[9];
    const float* w_bond_final = (const float*)d_in[10];
    const float* b_bond_final = (const float*)d_in[11];
    const float* w_z = (const float*)d_in[12];
    const float* b_z = (const float*)d_in[13];
    const float* w_r = (const float*)d_in[14];
    const float* b_r = (const float*)d_in[15];
    const float* u_  = (const float*)d_in[16];
    const float* w_m = (const float*)d_in[17];
    const float* b_m = (const float*)d_in[18];
    const float* w_n = (const float*)d_in[19];
    const float* b_n = (const float*)d_in[20];
    const float* u_n = (const float*)d_in[21];

    const int* i_idx = connect;
    const int* j_idx = connect + NE;
    const int* ij    = bnb;
    const int* ki    = bnb + NB;

    const size_t EBH = (size_t)NE * DD * 2;        // 102,400,000 (bf16 E-buffer)
    const size_t B_WT = (size_t)5088 * 256 * 2;    // all packed weights, 2.6 MB
    const int NEpad = 196 * 1024;
    const int NNpad = 98 * 1024;
    const size_t B_CSR = (size_t)NEpad * 8 + (size_t)NB * 4
                       + (size_t)NNpad * 8 + (size_t)NE * 4 + 2048;
    const size_t NEED_F = 3 * EBH + B_WT + B_CSR;  // fallback: PR,MB,TR  ~315 MB
    const size_t NEED_H = 5 * EBH + B_WT + B_CSR;  // hoist: +PZ,+PM      ~520 MB

    float* out_node = (float*)d_out;
    float* out_bond = out_node + (size_t)NN * DD;

    if (ws_size < NEED_F) {
        fill_kernel<<<2048, 256, 0, stream>>>((float*)d_out, 1e6f, (long)out_size / 4);
        return;
    }
    const bool HOIST = (ws_size >= NEED_H);

    char* base = (char*)d_ws;
    bf16* PR = (bf16*)base;                       base += EBH;
    bf16* MB = (bf16*)base;                       base += EBH;
    bf16* TR = (bf16*)base;                       base += EBH;   // aliases AGG + final-node scratch
    bf16* PZ = nullptr; bf16* PM = nullptr;
    if (HOIST) { PZ = (bf16*)base; base += EBH; PM = (bf16*)base; base += EBH; }
    char* wt = base;                              base += B_WT;
    int* offE  = (int*)base;                      base += (size_t)NEpad * 4;
    int* curE  = (int*)base;                      base += (size_t)NEpad * 4;
    int* nbLst = (int*)base;                      base += (size_t)NB * 4;
    int* offN  = (int*)base;                      base += (size_t)NNpad * 4;
    int* curN  = (int*)base;                      base += (size_t)NNpad * 4;
    int* agLst = (int*)base;                      base += (size_t)NE * 4;
    int* bsumE = (int*)base;                      base += 1024;
    int* bsumN = (int*)base;

    bf16* AGG = TR;
    bf16* R = (bf16*)out_bond;
    bf16* S = R + (size_t)NE * DD;

    auto wtAlloc = [&](size_t elems) { bf16* p = (bf16*)wt; wt += elems * 2; return p; };
    bf16* WTn0   = wtAlloc(160 * 256);   // w_node
    bf16* WTn    = wtAlloc(160 * 256);   // w_n
    bf16* WTr    = wtAlloc(160 * 256);   // w_r[0:147]
    bf16* WTb    = wtAlloc(160 * 256);   // w_bond
    bf16* WTzIB  = wtAlloc(160 * 256);   // w_z[0:147]
    bf16* WTmIB  = wtAlloc(160 * 256);   // w_m[0:147]
    bf16* WTr2   = wtAlloc(256 * 256);   // w_r[147:403]
    bf16* WTz2   = wtAlloc(256 * 256);   // w_z[147:403]
    bf16* WTu    = wtAlloc(256 * 256);   // u
    bf16* WTnu5  = wtAlloc(512 * 256);   // u_n (512)
    bf16* WTz672 = wtAlloc(672 * 256);   // w_z(403)           (fallback)
    bf16* WTm672 = wtAlloc(672 * 256);   // w_m|0|u            (fallback)
    bf16* WTnu6  = wtAlloc(672 * 256);   // w_n|u_n            (fallback)
    bf16* WTbf   = wtAlloc(416 * 256);   // w_bond_final(403)
    bf16* WTnf   = wtAlloc(416 * 256);   // w_node_final(389)

    const float* w_r2 = w_r + (size_t)FIB * DD;
    const float* w_z2 = w_z + (size_t)FIB * DD;

    auto packG = [&](int ktpad) { return (256 * ktpad + 255) / 256; };
    pack_wt<<<packG(160), 256, 0, stream>>>(w_node, FN, nullptr, 0, nullptr, 0, 160, WTn0);
    pack_wt<<<packG(160), 256, 0, stream>>>(w_n, FN, nullptr, 0, nullptr, 0, 160, WTn);
    pack_wt<<<packG(160), 256, 0, stream>>>(w_r, FIB, nullptr, 0, nullptr, 0, 160, WTr);
    pack_wt<<<packG(160), 256, 0, stream>>>(w_bond, FIB, nullptr, 0, nullptr, 0, 160, WTb);
    pack_wt<<<packG(160), 256, 0, stream>>>(w_z, FIB, nullptr, 0, nullptr, 0, 160, WTzIB);
    pack_wt<<<packG(160), 256, 0, stream>>>(w_m, FIB, nullptr, 0, nullptr, 0, 160, WTmIB);
    pack_wt<<<packG(256), 256, 0, stream>>>(w_r2, DD, nullptr, 0, nullptr, 0, 256, WTr2);
    pack_wt<<<packG(256), 256, 0, stream>>>(w_z2, DD, nullptr, 0, nullptr, 0, 256, WTz2);
    pack_wt<<<packG(256), 256, 0, stream>>>(u_, DD, nullptr, 0, nullptr, 0, 256, WTu);
    pack_wt<<<packG(512), 256, 0, stream>>>(u_n, 2 * DD, nullptr, 0, nullptr, 0, 512, WTnu5);
    pack_wt<<<packG(672), 256, 0, stream>>>(w_z, 403, nullptr, 0, nullptr, 0, 672, WTz672);
    pack_wt<<<packG(672), 256, 0, stream>>>(w_m, FIB, nullptr, DD, u_, DD, 672, WTm672);
    pack_wt<<<packG(672), 256, 0, stream>>>(w_n, FN, u_n, 2 * DD, nullptr, 0, 672, WTnu6);
    pack_wt<<<packG(416), 256, 0, stream>>>(w_bond_final, 403, nullptr, 0, nullptr, 0, 416, WTbf);
    pack_wt<<<packG(416), 256, 0, stream>>>(w_node_final, 389, nullptr, 0, nullptr, 0, 416, WTnf);

    // ---- CSR build (layer-invariant) ----
    fill_kernel<<<256, 256, 0, stream>>>((float*)offE, 0.f, NEpad / 4);
    fill_kernel<<<256, 256, 0, stream>>>((float*)offN, 0.f, NNpad / 4);
    count_kernel<<<(NB + 255) / 256, 256, 0, stream>>>(ij, NB, offE);
    count_kernel<<<(NE + 255) / 256, 256, 0, stream>>>(j_idx, NE, offN);
    scan_block<<<196, 256, 0, stream>>>(offE, bsumE);
    scan_bsum<<<1, 256, 0, stream>>>(bsumE, 196);
    scan_add<<<NEpad / 256, 256, 0, stream>>>(offE, bsumE, NEpad);
    scan_block<<<98, 256, 0, stream>>>(offN, bsumN);
    scan_bsum<<<1, 256, 0, stream>>>(bsumN, 98);
    scan_add<<<NNpad / 256, 256, 0, stream>>>(offN, bsumN, NNpad);
    copy_int<<<NEpad / 256, 256, 0, stream>>>(curE, offE, NEpad);
    copy_int<<<NNpad / 256, 256, 0, stream>>>(curN, offN, NNpad);
    fill_nb_list<<<(NB + 255) / 256, 256, 0, stream>>>(ij, ki, curE, nbLst);
    fill_agg_list<<<(NE + 255) / 256, 256, 0, stream>>>(j_idx, curN, agLst);

    dim3 gB((NE + 127) / 128, 2);     // 1563 x 2
    dim3 gN((NN + 127) / 128, 2);     // 782 x 2
    dim3 gNf((NN + 127) / 128, 1);    // 782 (BN=256)

    if (HOIST) {
        bf16* MN = (bf16*)out_node;                      // 51.2 MB
        bf16* PN = MN + (size_t)NN * DD;                 // 51.2 MB
        // layer-invariant hoists
        mgemm<128, 0, -1, -1, -1, 1><<<gN, 256, 0, stream>>>(
            node, FN, nullptr, 0, nullptr, 0, nullptr, 0, nullptr,
            WTn0, nullptr, 160, b_node, nullptr, nullptr, MN, nullptr, NN);
        mgemm<128, 0, -1, -1, -1, 0><<<gN, 256, 0, stream>>>(
            node, FN, nullptr, 0, nullptr, 0, nullptr, 0, nullptr,
            WTn, nullptr, 160, b_n, nullptr, nullptr, PN, nullptr, NN);
        mgemm<128, 2, 0, -1, -1, 0><<<gB, 256, 0, stream>>>(
            node, FN, bond, FB, nullptr, 0, nullptr, 0, i_idx,
            WTr, nullptr, 160, b_r, nullptr, nullptr, PR, nullptr, NE);
        mgemm<128, 2, 0, -1, -1, 1><<<gB, 256, 0, stream>>>(
            node, FN, bond, FB, nullptr, 0, nullptr, 0, i_idx,
            WTb, nullptr, 160, b_bond, nullptr, nullptr, MB, nullptr, NE);
        mgemm<128, 2, 0, -1, -1, 4><<<gB, 256, 0, stream>>>(
            node, FN, bond, FB, nullptr, 0, nullptr, 0, i_idx,
            WTzIB, WTmIB, 160, b_z, b_m, nullptr, PZ, PM, NE);

        for (int l = 0; l < 3; l++) {
            seg_s_kernel<<<(NE + 3) / 4, 256, 0, stream>>>(MB, offE, nbLst, S, NE);
            bgemm<128, 1, 0, 0><<<gB, 256, 0, stream>>>(
                MB, nullptr, WTr2, nullptr, nullptr, nullptr, TR, NE);
            seg_r_kernel<<<(NE + 3) / 4, 256, 0, stream>>>(MB, TR, PR, offE, nbLst, R);
            bgemm<128, 2, 1, 1><<<gB, 512, 0, stream>>>(
                S, R, WTz2, WTu, PZ, PM, MB, NE);
            seg_s_kernel<<<(NN + 3) / 4, 256, 0, stream>>>(MB, offN, agLst, AGG, NN);
            bgemm<256, 2, 0, 2><<<gNf, 512, 0, stream>>>(
                MN, AGG, WTnu5, nullptr, PN, nullptr, MN, NN);
        }

        mgemm<128, 2, 0, 1, -1, 2><<<gB, 256, 0, stream>>>(
            node, FN, bond, FB, MB, DD, nullptr, 0, i_idx,
            WTbf, nullptr, 416, b_bond_final, nullptr, nullptr, out_bond, nullptr, NE);
        // final node -> scratch (TR region), then D2D into out_node (MN/PN live there)
        float* scratch = (float*)TR;
        mgemm<256, 0, 1, -1, -1, 2><<<gNf, 512, 0, stream>>>(
            node, FN, MN, DD, nullptr, 0, nullptr, 0, nullptr,
            WTnf, nullptr, 416, b_node_final, nullptr, nullptr, scratch, nullptr, NN);
        hipMemcpyAsync(out_node, scratch, (size_t)NN * DD * 4,
                       hipMemcpyDeviceToDevice, stream);
    } else {
        float* MN = out_node;   // f32 MN in d_out
        mgemm<128, 0, -1, -1, -1, 2><<<gN, 256, 0, stream>>>(
            node, FN, nullptr, 0, nullptr, 0, nullptr, 0, nullptr,
            WTn0, nullptr, 160, b_node, nullptr, nullptr, MN, nullptr, NN);
        mgemm<128, 2, 0, -1, -1, 0><<<gB, 256, 0, stream>>>(
            node, FN, bond, FB, nullptr, 0, nullptr, 0, i_idx,
            WTr, nullptr, 160, b_r, nullptr, nullptr, PR, nullptr, NE);
        mgemm<128, 2, 0, -1, -1, 1><<<gB, 256, 0, stream>>>(
            node, FN, bond, FB, nullptr, 0, nullptr, 0, i_idx,
            WTb, nullptr, 160, b_bond, nullptr, nullptr, MB, nullptr, NE);

        for (int l = 0; l < 3; l++) {
            seg_s_kernel<<<(NE + 3) / 4, 256, 0, stream>>>(MB, offE, nbLst, S, NE);
            bgemm<128, 1, 0, 0><<<gB, 256, 0, stream>>>(
                MB, nullptr, WTr2, nullptr, nullptr, nullptr, TR, NE);
            seg_r_kernel<<<(NE + 3) / 4, 256, 0, stream>>>(MB, TR, PR, offE, nbLst, R);
            mgemm<128, 2, 0, 1, 1, 3><<<gB, 256, 0, stream>>>(
                node, FN, bond, FB, S, DD, R, DD, i_idx,
                WTz672, WTm672, 672, b_z, b_m, S, MB, nullptr, NE);
            seg_s_kernel<<<(NN + 3) / 4, 256, 0, stream>>>(MB, offN, agLst, AGG, NN);
            mgemm<256, 0, 0, 1, -1, 2><<<gNf, 512, 0, stream>>>(
                node, FN, MN, DD, AGG, DD, nullptr, 0, nullptr,
                WTnu6, nullptr, 672, b_n, nullptr, nullptr, MN, nullptr, NN);
        }

        mgemm<128, 2, 0, 1, -1, 2><<<gB, 256, 0, stream>>>(
            node, FN, bond, FB, MB, DD, nullptr, 0, i_idx,
            WTbf, nullptr, 416, b_bond_final, nullptr, nullptr, out_bond, nullptr, NE);
        mgemm<256, 0, 0, -1, -1, 2><<<gNf, 512, 0, stream>>>(
            node, FN, MN, DD, nullptr, 0, nullptr, 0, nullptr,
            WTnf, nullptr, 416, b_node_final, nullptr, nullptr, out_node, nullptr, NN);
    }
}

// Round 7
// 3048.827 us; speedup vs baseline: 9.0353x; 1.3918x over previous
//
#include <hip/hip_runtime.h>
#include <hip/hip_bf16.h>

#define NN 100000   // nodes
#define NE 200000   // bonds
#define NB 600000   // bond neighbours
#define FN 133
#define FB 14
#define FIB 147     // FN+FB
#define DD 256

typedef __hip_bfloat16 bf16;
typedef __attribute__((ext_vector_type(8))) short short8;   // 8 bf16 = 4 VGPR
typedef __attribute__((ext_vector_type(4))) float f32x4;

__device__ __forceinline__ float hswish(float x) {
    float c = fminf(fmaxf(x + 3.f, 0.f), 6.f);
    return x * c * (1.f / 6.f);
}
__device__ __forceinline__ float sigmoidf(float x) {
    return 1.f / (1.f + __expf(-x));
}
__device__ __forceinline__ float bf2f(unsigned short u) {
    union { unsigned int i; float f; } c; c.i = (unsigned int)u << 16; return c.f;
}
__device__ __forceinline__ unsigned short f2bf(float v) {
    bf16 b = __float2bfloat16(v);
    unsigned short u; __builtin_memcpy(&u, &b, 2); return u;
}

// ---------------- fill (zero counts + ws-guard sentinel) ----------------
__global__ __launch_bounds__(256) void fill_kernel(float* __restrict__ p, float v, long n4) {
    long i = (long)blockIdx.x * 256 + threadIdx.x;
    long st = (long)gridDim.x * 256;
    float4 z = {v, v, v, v};
    for (; i < n4; i += st) ((float4*)p)[i] = z;
}

// ---------------- IB build: IBbf[e][160] = [node[i_idx[e]] | bond[e] | 0]
__global__ __launch_bounds__(256) void build_ib_bf(
    const float* __restrict__ node, const float* __restrict__ bond,
    const int* __restrict__ i_idx, bf16* __restrict__ IB)
{
    int t = blockIdx.x * 256 + threadIdx.x;
    int row = t >> 6;
    if (row >= NE) return;
    int lane = t & 63;
    if (lane >= 40) return;
    int src = i_idx[row];
    int c = lane * 4;
    unsigned short us[4];
    #pragma unroll
    for (int j = 0; j < 4; j++) {
        int k = c + j;
        float v = 0.f;
        if (k < FN)       v = node[(size_t)src * FN + k];
        else if (k < FIB) v = bond[(size_t)row * FB + (k - FN)];
        us[j] = f2bf(v);
    }
    ushort4 o = {us[0], us[1], us[2], us[3]};
    *(ushort4*)((unsigned short*)IB + (size_t)row * 160 + c) = o;
}

// ---------------- CSR build helpers -------------------------------------
__global__ __launch_bounds__(256) void count_kernel(
    const int* __restrict__ idx, int n, int* __restrict__ cnt)
{
    int i = blockIdx.x * 256 + threadIdx.x;
    if (i < n) atomicAdd(&cnt[idx[i]], 1);
}

__global__ __launch_bounds__(256) void scan_block(int* __restrict__ data, int* __restrict__ bsum)
{
    __shared__ int lds[256];
    int base = blockIdx.x * 1024 + threadIdx.x * 4;
    int c0 = data[base], c1 = data[base + 1], c2 = data[base + 2], c3 = data[base + 3];
    int t = c0 + c1 + c2 + c3;
    lds[threadIdx.x] = t;
    __syncthreads();
    int x = t;
    for (int off = 1; off < 256; off <<= 1) {
        int y = (threadIdx.x >= off) ? lds[threadIdx.x - off] : 0;
        __syncthreads();
        x += y; lds[threadIdx.x] = x;
        __syncthreads();
    }
    int excl = x - t;
    data[base] = excl; data[base + 1] = excl + c0;
    data[base + 2] = excl + c0 + c1; data[base + 3] = excl + c0 + c1 + c2;
    if (threadIdx.x == 255) bsum[blockIdx.x] = x;
}

__global__ __launch_bounds__(256) void scan_bsum(int* __restrict__ bsum, int n)
{
    __shared__ int lds[256];
    int t = (threadIdx.x < n) ? bsum[threadIdx.x] : 0;
    lds[threadIdx.x] = t;
    __syncthreads();
    int x = t;
    for (int off = 1; off < 256; off <<= 1) {
        int y = (threadIdx.x >= off) ? lds[threadIdx.x - off] : 0;
        __syncthreads();
        x += y; lds[threadIdx.x] = x;
        __syncthreads();
    }
    if (threadIdx.x < n) bsum[threadIdx.x] = x - t;
}

__global__ __launch_bounds__(256) void scan_add(
    int* __restrict__ data, const int* __restrict__ bsum, int n)
{
    int i = blockIdx.x * 256 + threadIdx.x;
    if (i < n) data[i] += bsum[i >> 10];
}

__global__ __launch_bounds__(256) void copy_int(
    int* __restrict__ dst, const int* __restrict__ src, int n)
{
    int i = blockIdx.x * 256 + threadIdx.x;
    if (i < n) dst[i] = src[i];
}

__global__ __launch_bounds__(256) void fill_nb_list(
    const int* __restrict__ ij, const int* __restrict__ ki,
    int* __restrict__ cur, int* __restrict__ lst)
{
    int e = blockIdx.x * 256 + threadIdx.x;
    if (e < NB) { int p = atomicAdd(&cur[ij[e]], 1); lst[p] = ki[e]; }
}

__global__ __launch_bounds__(256) void fill_agg_list(
    const int* __restrict__ jidx, int* __restrict__ cur, int* __restrict__ lst)
{
    int e = blockIdx.x * 256 + threadIdx.x;
    if (e < NE) { int p = atomicAdd(&cur[jidx[e]], 1); lst[p] = e; }
}

// ---------------- CSR segment sums (one wave per segment, no atomics) ---
__global__ __launch_bounds__(256) void seg_s_kernel(
    const bf16* __restrict__ MB, const int* __restrict__ off,
    const int* __restrict__ lst, bf16* __restrict__ S, int nseg)
{
    int sid = blockIdx.x * 4 + (threadIdx.x >> 6);
    if (sid >= nseg) return;
    int lane = threadIdx.x & 63;
    int b = off[sid], e = off[sid + 1];
    float a0 = 0, a1 = 0, a2 = 0, a3 = 0;
    for (int t = b; t < e; t++) {
        int src = lst[t];
        ushort4 u = *(const ushort4*)((const unsigned short*)MB + (size_t)src * DD + lane * 4);
        a0 += bf2f(u.x); a1 += bf2f(u.y); a2 += bf2f(u.z); a3 += bf2f(u.w);
    }
    ushort4 o = {f2bf(a0), f2bf(a1), f2bf(a2), f2bf(a3)};
    *(ushort4*)((unsigned short*)S + (size_t)sid * DD + lane * 4) = o;
}

__global__ __launch_bounds__(256) void seg_r_kernel(
    const bf16* __restrict__ MB, const bf16* __restrict__ TR,
    const bf16* __restrict__ PR, const int* __restrict__ off,
    const int* __restrict__ lst, bf16* __restrict__ R)
{
    int sid = blockIdx.x * 4 + (threadIdx.x >> 6);
    if (sid >= NE) return;
    int lane = threadIdx.x & 63;
    ushort4 up = *(const ushort4*)((const unsigned short*)PR + (size_t)sid * DD + lane * 4);
    float p0 = bf2f(up.x), p1 = bf2f(up.y), p2 = bf2f(up.z), p3 = bf2f(up.w);
    int b = off[sid], e = off[sid + 1];
    float a0 = 0, a1 = 0, a2 = 0, a3 = 0;
    for (int t = b; t < e; t++) {
        int src = lst[t];
        ushort4 ut = *(const ushort4*)((const unsigned short*)TR + (size_t)src * DD + lane * 4);
        ushort4 um = *(const ushort4*)((const unsigned short*)MB + (size_t)src * DD + lane * 4);
        a0 += sigmoidf(p0 + bf2f(ut.x)) * bf2f(um.x);
        a1 += sigmoidf(p1 + bf2f(ut.y)) * bf2f(um.y);
        a2 += sigmoidf(p2 + bf2f(ut.z)) * bf2f(um.z);
        a3 += sigmoidf(p3 + bf2f(ut.w)) * bf2f(um.w);
    }
    ushort4 o = {f2bf(a0), f2bf(a1), f2bf(a2), f2bf(a3)};
    *(ushort4*)((unsigned short*)R + (size_t)sid * DD + lane * 4) = o;
}

// ------------- weight pack: dst[n][k] = bf16(seg(k, n)), K-padded -------
__global__ __launch_bounds__(256) void pack_wt(
    const float* W1, int K1, const float* W2, int K2, const float* W3, int K3,
    int KTpad, bf16* dst)
{
    int idx = blockIdx.x * 256 + threadIdx.x;
    if (idx >= 256 * KTpad) return;
    int n = idx / KTpad, k = idx % KTpad;
    float v = 0.f;
    if (k < K1)                { if (W1) v = W1[(size_t)k * DD + n]; }
    else if (k < K1 + K2)      { if (W2) v = W2[(size_t)(k - K1) * DD + n]; }
    else if (k < K1 + K2 + K3) { if (W3) v = W3[(size_t)(k - K1 - K2) * DD + n]; }
    dst[(size_t)n * KTpad + k] = __float2bfloat16(v);
}

// ---------------- unified MFMA GEMM, all-vector staging -----------------
// A = concat of seg1, seg2 (per-segment dtype/stride; kw mult of 32).
// DUAL: 0 none; 1 shared-A two-W; 2 split-A two-W (A1=seg1, A2 via seg2 desc)
// EPB: 0 lin(+b1)->bf16; 1 hsw(+b1)->bf16;
//      2 dual: out1=hsw(acc1+b1), out2=acc2+b2 (bf16);
//      3 dual: out1=acc1+b1, out2=acc2+b2 (bf16);
//      4 blend: z=sig(acc1+PZ), m=tanh(acc2+PM), out1=(1-z)*A1+z*m (bf16);
//      5 hsw(acc1 + PX[idx]) -> bf16  (PX passed as PZb);
//      6 hsw(acc1 + b1) -> f32
template <int BN, int NT, int DUAL, int EPB>
__global__ __launch_bounds__(NT) void bg(
    const void* __restrict__ A1, int a1stride, int a1kw, int a1real, int a1f32,
    const void* __restrict__ A2, int a2stride, int a2kw, int a2real, int a2f32,
    const bf16* __restrict__ WT1, const bf16* __restrict__ WT2, int KT,
    const float* __restrict__ bias1, const float* __restrict__ bias2,
    const bf16* __restrict__ PZb, const bf16* __restrict__ PMb,
    void* __restrict__ out1, void* __restrict__ out2, int M)
{
    constexpr int BM = 128;
    constexpr int nWc = BN / 64;
    constexpr int nWr = (NT / 64) / nWc;
    constexpr int MSPAN = BM / nWr;
    constexpr int MFR = MSPAN / 16;
    __shared__ __align__(16) unsigned short As[BM * 40];
    __shared__ __align__(16) unsigned short As2[(DUAL == 2 ? BM : 8) * 40];
    __shared__ __align__(16) unsigned short Bs[BN * 40];
    __shared__ __align__(16) unsigned short Bs2[(DUAL ? BN : 8) * 40];
    const int tid = threadIdx.x;
    const int row0 = blockIdx.x * BM, col0 = blockIdx.y * BN;
    const int lane = tid & 63, w = tid >> 6;
    const int wr = w / nWc, wc = w % nWc;
    const int fr = lane & 15, ko = (lane >> 4) * 8;

    f32x4 acc[MFR][4] = {};
    f32x4 acc2[DUAL ? MFR : 1][DUAL ? 4 : 1] = {};

    for (int k0 = 0; k0 < KT; k0 += 32) {
        // ---- A staging
        #pragma unroll
        for (int it = 0; it < BM * 4 / NT; ++it) {
            int mloc = (tid >> 2) + it * (NT / 4);
            int mg = row0 + mloc;
            bool mok = (mg < M);
            int kq = (tid & 3) * 8;
            int kg = k0 + kq;
            if (DUAL == 2) {
                uint4 v1 = {0, 0, 0, 0}, v2 = {0, 0, 0, 0};
                if (mok) {
                    v1 = *(const uint4*)((const bf16*)A1 + (size_t)mg * a1stride + kg);
                    v2 = *(const uint4*)((const bf16*)A2 + (size_t)mg * a2stride + kg);
                }
                *(uint4*)&As[mloc * 40 + kq] = v1;
                *(uint4*)&As2[mloc * 40 + kq] = v2;
            } else {
                const void* p; int stride, real, isf; int kk;
                if (kg < a1kw) { p = A1; stride = a1stride; real = a1real; isf = a1f32; kk = kg; }
                else           { p = A2; stride = a2stride; real = a2real; isf = a2f32; kk = kg - a1kw; }
                uint4 v = {0, 0, 0, 0};
                if (mok) {
                    if (!isf) {
                        v = *(const uint4*)((const bf16*)p + (size_t)mg * stride + kk);
                    } else {
                        const float* fp = (const float*)p + (size_t)mg * stride;
                        unsigned short us[8];
                        #pragma unroll
                        for (int j = 0; j < 8; j++)
                            us[j] = (kk + j < real) ? f2bf(fp[kk + j]) : (unsigned short)0;
                        v.x = us[0] | ((unsigned)us[1] << 16);
                        v.y = us[2] | ((unsigned)us[3] << 16);
                        v.z = us[4] | ((unsigned)us[5] << 16);
                        v.w = us[6] | ((unsigned)us[7] << 16);
                    }
                }
                *(uint4*)&As[mloc * 40 + kq] = v;
            }
        }
        // ---- B staging
        #pragma unroll
        for (int it = 0; it < BN * 4 / NT; ++it) {
            int nloc = (tid >> 2) + it * (NT / 4);
            int kq = (tid & 3) * 8;
            *(uint4*)&Bs[nloc * 40 + kq] =
                *(const uint4*)&WT1[(size_t)(col0 + nloc) * KT + k0 + kq];
            if (DUAL)
                *(uint4*)&Bs2[nloc * 40 + kq] =
                    *(const uint4*)&WT2[(size_t)(col0 + nloc) * KT + k0 + kq];
        }
        __syncthreads();
        short8 a1f[MFR], b1f[4];
        short8 a2f[DUAL == 2 ? MFR : 1], b2f[DUAL ? 4 : 1];
        #pragma unroll
        for (int mf = 0; mf < MFR; mf++) {
            a1f[mf] = *(const short8*)&As[(wr * MSPAN + mf * 16 + fr) * 40 + ko];
            if (DUAL == 2)
                a2f[mf] = *(const short8*)&As2[(wr * MSPAN + mf * 16 + fr) * 40 + ko];
        }
        #pragma unroll
        for (int nf = 0; nf < 4; nf++) {
            b1f[nf] = *(const short8*)&Bs[(wc * 64 + nf * 16 + fr) * 40 + ko];
            if (DUAL)
                b2f[nf] = *(const short8*)&Bs2[(wc * 64 + nf * 16 + fr) * 40 + ko];
        }
        #pragma unroll
        for (int mf = 0; mf < MFR; mf++)
            #pragma unroll
            for (int nf = 0; nf < 4; nf++) {
                acc[mf][nf] = __builtin_amdgcn_mfma_f32_16x16x32_bf16(a1f[mf], b1f[nf], acc[mf][nf], 0, 0, 0);
                if (DUAL)
                    acc2[mf][nf] = __builtin_amdgcn_mfma_f32_16x16x32_bf16(
                        DUAL == 2 ? a2f[mf] : a1f[mf], b2f[nf], acc2[mf][nf], 0, 0, 0);
            }
        __syncthreads();
    }

    #pragma unroll
    for (int mf = 0; mf < MFR; mf++) {
        #pragma unroll
        for (int i = 0; i < 4; i++) {
            int mloc = wr * MSPAN + mf * 16 + (lane >> 4) * 4 + i;
            int gm = row0 + mloc;
            if (gm >= M) continue;
            #pragma unroll
            for (int nf = 0; nf < 4; nf++) {
                int gc = col0 + wc * 64 + nf * 16 + fr;
                size_t idx = (size_t)gm * DD + gc;
                float v = acc[mf][nf][i];
                if (EPB == 0) {
                    if (bias1) v += bias1[gc];
                    ((bf16*)out1)[idx] = __float2bfloat16(v);
                } else if (EPB == 1) {
                    ((bf16*)out1)[idx] = __float2bfloat16(hswish(v + bias1[gc]));
                } else if (EPB == 2) {
                    ((bf16*)out1)[idx] = __float2bfloat16(hswish(v + bias1[gc]));
                    ((bf16*)out2)[idx] = __float2bfloat16(acc2[mf][nf][i] + bias2[gc]);
                } else if (EPB == 3) {
                    ((bf16*)out1)[idx] = __float2bfloat16(v + bias1[gc]);
                    ((bf16*)out2)[idx] = __float2bfloat16(acc2[mf][nf][i] + bias2[gc]);
                } else if (EPB == 4) {
                    float z  = sigmoidf(v + __bfloat162float(PZb[idx]));
                    float mm = tanhf(acc2[mf][nf][i] + __bfloat162float(PMb[idx]));
                    float s  = __bfloat162float(((const bf16*)A1)[idx]);
                    ((bf16*)out1)[idx] = __float2bfloat16((1.f - z) * s + z * mm);
                } else if (EPB == 5) {
                    ((bf16*)out1)[idx] =
                        __float2bfloat16(hswish(v + __bfloat162float(PZb[idx])));
                } else {  // EPB == 6
                    ((float*)out1)[idx] = hswish(v + bias1[gc]);
                }
            }
        }
    }
}

extern "C" void kernel_launch(void* const* d_in, const int* in_sizes, int n_in,
                              void* d_out, int out_size, void* d_ws, size_t ws_size,
                              hipStream_t stream)
{
    const float* node  = (const float*)d_in[0];
    const float* bond  = (const float*)d_in[1];
    const int* connect = (const int*)d_in[2];
    const int* bnb     = (const int*)d_in[3];
    const float* w_node       = (const float*)d_in[4];
    const float* b_node       = (const float*)d_in[5];
    const float* w_node_final = (const float*)d_in[6];
    const float* b_node_final = (const float*)d_in[7];
    const float* w_bond       = (const float*)d_in[8];
    const float* b_bond       = (const float*)d_in[9];
    const float* w_bond_final = (const float*)d_in[10];
    const float* b_bond_final = (const float*)d_in[11];
    const float* w_z = (const float*)d_in[12];
    const float* b_z = (const float*)d_in[13];
    const float* w_r = (const float*)d_in[14];
    const float* b_r = (const float*)d_in[15];
    const float* u_  = (const float*)d_in[16];
    const float* w_m = (const float*)d_in[17];
    const float* b_m = (const float*)d_in[18];
    const float* w_n = (const float*)d_in[19];
    const float* b_n = (const float*)d_in[20];
    const float* u_n = (const float*)d_in[21];

    const int* i_idx = connect;
    const int* j_idx = connect + NE;
    const int* ij    = bnb;
    const int* ki    = bnb + NB;

    const size_t EBH = (size_t)NE * DD * 2;        // 102,400,000
    const size_t B_WT = (size_t)3072 * 256 * 2;    // 1.57 MB packed weights
    const int NEpad = 196 * 1024;
    const int NNpad = 98 * 1024;
    const size_t B_CSR = (size_t)NEpad * 8 + (size_t)NB * 4
                       + (size_t)NNpad * 8 + (size_t)NE * 4 + 2048;
    const size_t NEED = 5 * EBH + B_WT + B_CSR;    // ~519.4 MB (known to fit)

    float* out_node = (float*)d_out;
    float* out_bond = out_node + (size_t)NN * DD;

    if (ws_size < NEED) {
        fill_kernel<<<2048, 256, 0, stream>>>((float*)d_out, 1e6f, (long)out_size / 4);
        return;
    }

    char* base = (char*)d_ws;
    bf16* PR = (bf16*)base;                       base += EBH;
    bf16* MB = (bf16*)base;                       base += EBH;
    bf16* TR = (bf16*)base;                       base += EBH;   // also IBbf + final-node scratch
    bf16* PZ = (bf16*)base;                       base += EBH;
    bf16* PM = (bf16*)base;                       base += EBH;
    char* wt = base;                              base += B_WT;
    int* offE  = (int*)base;                      base += (size_t)NEpad * 4;
    int* curE  = (int*)base;                      base += (size_t)NEpad * 4;
    int* nbLst = (int*)base;                      base += (size_t)NB * 4;
    int* offN  = (int*)base;                      base += (size_t)NNpad * 4;
    int* curN  = (int*)base;                      base += (size_t)NNpad * 4;
    int* agLst = (int*)base;                      base += (size_t)NE * 4;
    int* bsumE = (int*)base;                      base += 1024;
    int* bsumN = (int*)base;

    bf16* IBbf = TR;                 // pre-loop + rebuilt post-loop
    bf16* AGG  = TR;                 // loop-internal (after TR consumed)
    float* scratchN = (float*)TR;    // final node f32 output
    bf16* R = (bf16*)out_bond;
    bf16* S = R + (size_t)NE * DD;
    bf16* MN = (bf16*)out_node;
    bf16* PN = MN + (size_t)NN * DD;

    auto wtAlloc = [&](size_t elems) { bf16* p = (bf16*)wt; wt += elems * 2; return p; };
    bf16* WTr  = wtAlloc(160 * 256);   // w_r[0:147]
    bf16* WTz1 = wtAlloc(160 * 256);   // w_z[0:147]
    bf16* WTb  = wtAlloc(160 * 256);   // w_bond
    bf16* WTm1 = wtAlloc(160 * 256);   // w_m
    bf16* WTn0 = wtAlloc(160 * 256);   // w_node
    bf16* WTn  = wtAlloc(160 * 256);   // w_n
    bf16* WTr2 = wtAlloc(256 * 256);   // w_r[147:403]
    bf16* WTz2 = wtAlloc(256 * 256);   // w_z[147:403]
    bf16* WTu  = wtAlloc(256 * 256);   // u
    bf16* WTnu = wtAlloc(512 * 256);   // u_n
    bf16* WTbf = wtAlloc(416 * 256);   // w_bond_final: 147 | 13 zeros | 256
    bf16* WTnf = wtAlloc(416 * 256);   // w_node_final: 133 | 27 zeros | 256

    const float* w_r2 = w_r + (size_t)FIB * DD;
    const float* w_z2 = w_z + (size_t)FIB * DD;

    auto packG = [&](int ktpad) { return (256 * ktpad + 255) / 256; };
    pack_wt<<<packG(160), 256, 0, stream>>>(w_r, FIB, nullptr, 0, nullptr, 0, 160, WTr);
    pack_wt<<<packG(160), 256, 0, stream>>>(w_z, FIB, nullptr, 0, nullptr, 0, 160, WTz1);
    pack_wt<<<packG(160), 256, 0, stream>>>(w_bond, FIB, nullptr, 0, nullptr, 0, 160, WTb);
    pack_wt<<<packG(160), 256, 0, stream>>>(w_m, FIB, nullptr, 0, nullptr, 0, 160, WTm1);
    pack_wt<<<packG(160), 256, 0, stream>>>(w_node, FN, nullptr, 0, nullptr, 0, 160, WTn0);
    pack_wt<<<packG(160), 256, 0, stream>>>(w_n, FN, nullptr, 0, nullptr, 0, 160, WTn);
    pack_wt<<<packG(256), 256, 0, stream>>>(w_r2, DD, nullptr, 0, nullptr, 0, 256, WTr2);
    pack_wt<<<packG(256), 256, 0, stream>>>(w_z2, DD, nullptr, 0, nullptr, 0, 256, WTz2);
    pack_wt<<<packG(256), 256, 0, stream>>>(u_, DD, nullptr, 0, nullptr, 0, 256, WTu);
    pack_wt<<<packG(512), 256, 0, stream>>>(u_n, 2 * DD, nullptr, 0, nullptr, 0, 512, WTnu);
    pack_wt<<<packG(416), 256, 0, stream>>>(w_bond_final, FIB, nullptr, 13,
                                            w_bond_final + (size_t)FIB * DD, DD, 416, WTbf);
    pack_wt<<<packG(416), 256, 0, stream>>>(w_node_final, FN, nullptr, 27,
                                            w_node_final + (size_t)FN * DD, DD, 416, WTnf);

    // ---- CSR build (layer-invariant) ----
    fill_kernel<<<256, 256, 0, stream>>>((float*)offE, 0.f, NEpad / 4);
    fill_kernel<<<256, 256, 0, stream>>>((float*)offN, 0.f, NNpad / 4);
    count_kernel<<<(NB + 255) / 256, 256, 0, stream>>>(ij, NB, offE);
    count_kernel<<<(NE + 255) / 256, 256, 0, stream>>>(j_idx, NE, offN);
    scan_block<<<196, 256, 0, stream>>>(offE, bsumE);
    scan_bsum<<<1, 256, 0, stream>>>(bsumE, 196);
    scan_add<<<NEpad / 256, 256, 0, stream>>>(offE, bsumE, NEpad);
    scan_block<<<98, 256, 0, stream>>>(offN, bsumN);
    scan_bsum<<<1, 256, 0, stream>>>(bsumN, 98);
    scan_add<<<NNpad / 256, 256, 0, stream>>>(offN, bsumN, NNpad);
    copy_int<<<NEpad / 256, 256, 0, stream>>>(curE, offE, NEpad);
    copy_int<<<NNpad / 256, 256, 0, stream>>>(curN, offN, NNpad);
    fill_nb_list<<<(NB + 255) / 256, 256, 0, stream>>>(ij, ki, curE, nbLst);
    fill_agg_list<<<(NE + 255) / 256, 256, 0, stream>>>(j_idx, curN, agLst);

    dim3 gB2(1563, 2);    // NE rows, BN=128
    dim3 gN2(782, 2);     // NN rows, BN=128
    dim3 gN1(782, 1);     // NN rows, BN=256
    int blkIB = NE * 64 / 256;

    // ---- pre-loop: build IB once, hoist all layer-invariant GEMMs ----
    build_ib_bf<<<blkIB, 256, 0, stream>>>(node, bond, i_idx, IBbf);
    bg<128, 512, 1, 3><<<gB2, 512, 0, stream>>>(        // PR, PZ
        IBbf, 160, 160, 160, 0, nullptr, 0, 0, 0, 0,
        WTr, WTz1, 160, b_r, b_z, nullptr, nullptr, PR, PZ, NE);
    bg<128, 512, 1, 2><<<gB2, 512, 0, stream>>>(        // MB, PM
        IBbf, 160, 160, 160, 0, nullptr, 0, 0, 0, 0,
        WTb, WTm1, 160, b_bond, b_m, nullptr, nullptr, MB, PM, NE);
    bg<128, 512, 1, 2><<<gN2, 512, 0, stream>>>(        // MN, PN
        node, FN, 160, FN, 1, nullptr, 0, 0, 0, 0,
        WTn0, WTn, 160, b_node, b_n, nullptr, nullptr, MN, PN, NN);

    for (int l = 0; l < 3; l++) {
        seg_s_kernel<<<(NE + 3) / 4, 256, 0, stream>>>(MB, offE, nbLst, S, NE);
        bg<128, 256, 0, 0><<<gB2, 256, 0, stream>>>(    // TR = MB @ w_r2
            MB, 256, 256, 256, 0, nullptr, 0, 0, 0, 0,
            WTr2, nullptr, 256, nullptr, nullptr, nullptr, nullptr, TR, nullptr, NE);
        seg_r_kernel<<<(NE + 3) / 4, 256, 0, stream>>>(MB, TR, PR, offE, nbLst, R);
        bg<128, 512, 2, 4><<<gB2, 512, 0, stream>>>(    // blend -> MB
            S, 256, 256, 256, 0, R, 256, 256, 256, 0,
            WTz2, WTu, 256, nullptr, nullptr, PZ, PM, MB, nullptr, NE);
        seg_s_kernel<<<(NN + 3) / 4, 256, 0, stream>>>(MB, offN, agLst, AGG, NN);
        bg<256, 512, 0, 5><<<gN1, 512, 0, stream>>>(    // MN = hsw([MN|AGG]@u_n + PN)
            MN, 256, 256, 256, 0, AGG, 256, 256, 256, 0,
            WTnu, nullptr, 512, nullptr, nullptr, PN, nullptr, MN, nullptr, NN);
    }

    // ---- finals ----
    build_ib_bf<<<blkIB, 256, 0, stream>>>(node, bond, i_idx, IBbf);  // TR slot free again
    bg<128, 512, 0, 6><<<gB2, 512, 0, stream>>>(        // bond final -> f32 out_bond
        IBbf, 160, 160, 160, 0, MB, 256, 256, 256, 0,
        WTbf, nullptr, 416, b_bond_final, nullptr, nullptr, nullptr, out_bond, nullptr, NE);
    bg<256, 512, 0, 6><<<gN1, 512, 0, stream>>>(        // node final -> f32 scratch
        node, FN, 160, FN, 1, MN, 256, 256, 256, 0,
        WTnf, nullptr, 416, b_node_final, nullptr, nullptr, nullptr, scratchN, nullptr, NN);
    hipMemcpyAsync(out_node, scratchN, (size_t)NN * DD * 4,
                   hipMemcpyDeviceToDevice, stream);
}